// Round 1
// baseline (1020.145 us; speedup 1.0000x reference)
//
#include <hip/hip_runtime.h>
#include <hip/hip_bf16.h>

#define BATCH   2
#define SEQ     2048
#define DMODEL  1024
#define DINNER  2048
#define DSTATE  64
#define NHEADS  32
#define HEADDIM 64
#define CONVDIM 2176
#define DINPROJ 4256
#define NCHUNK  32          // SEQ / 64
#define EPSF    1e-5f

// ---------------------------------------------------------------- LayerNorm
__global__ __launch_bounds__(256) void ln_kernel(
    const float* __restrict__ x, const float* __restrict__ w,
    const float* __restrict__ bv, float* __restrict__ h) {
    int row = blockIdx.x;                    // b*l  (4096 rows)
    const float* xr = x + (size_t)row * DMODEL;
    float* hr = h + (size_t)row * DMODEL;
    int t = threadIdx.x;
    float4 v = ((const float4*)xr)[t];       // 1024/4 = 256 float4, one per thread
    float s  = v.x + v.y + v.z + v.w;
    float ss = v.x*v.x + v.y*v.y + v.z*v.z + v.w*v.w;
    for (int o = 32; o > 0; o >>= 1) { s += __shfl_down(s, o); ss += __shfl_down(ss, o); }
    __shared__ float red[2][4];
    int wid = t >> 6, lane = t & 63;
    if (lane == 0) { red[0][wid] = s; red[1][wid] = ss; }
    __syncthreads();
    if (t == 0) {
        float a = 0, b2 = 0;
        for (int i = 0; i < 4; i++) { a += red[0][i]; b2 += red[1][i]; }
        red[0][0] = a; red[1][0] = b2;
    }
    __syncthreads();
    float mean = red[0][0] * (1.f / DMODEL);
    float var  = red[1][0] * (1.f / DMODEL) - mean * mean;
    float rstd = rsqrtf(var + EPSF);
    for (int i = t; i < DMODEL; i += 256)
        hr[i] = (xr[i] - mean) * rstd * w[i] + bv[i];
}

// ---------------------------------------------------------------- fp32 GEMM
// C[M,N] = A[M,K] @ B[K,N] (+ resid).  64x64 tile, BK=16, 4x4 per thread.
__global__ __launch_bounds__(256) void gemm64_kernel(
    const float* __restrict__ A, const float* __restrict__ B,
    float* __restrict__ C, int M, int N, int K,
    const float* __restrict__ resid) {
    __shared__ float As[64][17];             // padded: conflict-free column reads
    __shared__ float Bs[16][64];
    int t = threadIdx.x;
    int tx = t & 15, ty = t >> 4;
    int m0 = blockIdx.y * 64, n0 = blockIdx.x * 64;
    float acc[4][4] = {};
    for (int k0 = 0; k0 < K; k0 += 16) {
        { // A tile: 64 rows x 16 cols
            int r = t >> 2, c = (t & 3) * 4;
            float4 v = *(const float4*)&A[(size_t)(m0 + r) * K + k0 + c];
            As[r][c] = v.x; As[r][c+1] = v.y; As[r][c+2] = v.z; As[r][c+3] = v.w;
        }
        { // B tile: 16 rows x 64 cols (guard last N tile)
            int r = t >> 4, c = (t & 15) * 4;
            int gc = n0 + c;
            const float* src = &B[(size_t)(k0 + r) * N + gc];
            if (gc + 3 < N) {
                *(float4*)&Bs[r][c] = *(const float4*)src;
            } else {
                for (int j = 0; j < 4; j++) Bs[r][c+j] = (gc + j < N) ? src[j] : 0.f;
            }
        }
        __syncthreads();
        #pragma unroll
        for (int kk = 0; kk < 16; kk++) {
            float a0 = As[ty*4+0][kk], a1 = As[ty*4+1][kk],
                  a2 = As[ty*4+2][kk], a3 = As[ty*4+3][kk];
            float4 bb = *(const float4*)&Bs[kk][tx*4];
            acc[0][0] += a0*bb.x; acc[0][1] += a0*bb.y; acc[0][2] += a0*bb.z; acc[0][3] += a0*bb.w;
            acc[1][0] += a1*bb.x; acc[1][1] += a1*bb.y; acc[1][2] += a1*bb.z; acc[1][3] += a1*bb.w;
            acc[2][0] += a2*bb.x; acc[2][1] += a2*bb.y; acc[2][2] += a2*bb.z; acc[2][3] += a2*bb.w;
            acc[3][0] += a3*bb.x; acc[3][1] += a3*bb.y; acc[3][2] += a3*bb.z; acc[3][3] += a3*bb.w;
        }
        __syncthreads();
    }
    for (int i = 0; i < 4; i++) {
        int gm = m0 + ty*4 + i;
        for (int j = 0; j < 4; j++) {
            int gn = n0 + tx*4 + j;
            if (gn < N) {
                float v = acc[i][j];
                if (resid) v += resid[(size_t)gm * N + gn];
                C[(size_t)gm * N + gn] = v;
            }
        }
    }
}

// ------------------------------------------------- causal depthwise conv + SiLU
__global__ __launch_bounds__(256) void conv_kernel(
    const float* __restrict__ zx, const float* __restrict__ cw,
    const float* __restrict__ cb, float* __restrict__ xs,
    float* __restrict__ Bm, float* __restrict__ Cm) {
    int idx = blockIdx.x * 256 + threadIdx.x;        // b*l*CONVDIM
    int ch = idx % CONVDIM;
    int bl = idx / CONVDIM;
    int b = bl / SEQ, tt = bl % SEQ;
    float acc = cb[ch];
    #pragma unroll
    for (int k = 0; k < 4; k++) {
        int tp = tt - 3 + k;
        if (tp >= 0)
            acc += zx[(size_t)(b * SEQ + tp) * DINPROJ + DINNER + ch] * cw[ch * 4 + k];
    }
    float s = acc / (1.f + expf(-acc));
    if (ch < DINNER)              xs[(size_t)bl * DINNER + ch] = s;
    else if (ch < DINNER+DSTATE)  Bm[bl * DSTATE + (ch - DINNER)] = s;
    else                          Cm[bl * DSTATE + (ch - DINNER - DSTATE)] = s;
}

// ---------------------------------------------------------------- dt softplus
__global__ __launch_bounds__(256) void dt_kernel(
    const float* __restrict__ zx, const float* __restrict__ dt_bias,
    float* __restrict__ dtb) {
    int idx = blockIdx.x * 256 + threadIdx.x;        // b*l*NHEADS
    int hh = idx % NHEADS;
    int bl = idx / NHEADS;
    float v = zx[(size_t)bl * DINPROJ + (DINNER + CONVDIM) + hh] + dt_bias[hh];
    dtb[idx] = (v > 20.f) ? v : log1pf(expf(v));
}

// ----------------------------------------- SSD: per-chunk local states + A_cs
// block = (b*NCHUNK + c)*NHEADS + h
__global__ __launch_bounds__(256) void ssd_states_kernel(
    const float* __restrict__ xs, const float* __restrict__ Bm,
    const float* __restrict__ dtb, const float* __restrict__ A_log,
    float* __restrict__ states, float* __restrict__ Acs_g) {
    int blk = blockIdx.x;
    int hh = blk % NHEADS;
    int bc = blk / NHEADS;
    int c = bc % NCHUNK, b = bc / NCHUNK;
    __shared__ float Xd[64][64];
    __shared__ float Bw[64][64];
    __shared__ float dts[64];
    __shared__ float acs[64];
    int t = threadIdx.x;
    float Ah = -expf(A_log[hh]);
    if (t < 64)
        dts[t] = dtb[(b * SEQ + c * 64 + t) * NHEADS + hh];
    __syncthreads();
    if (t == 0) {
        float cum = 0.f;
        for (int l = 0; l < 64; l++) { cum += dts[l] * Ah; acs[l] = cum; }
    }
    __syncthreads();
    float alast = acs[63];
    if (t < 64)
        Acs_g[((b * NHEADS + hh) * NCHUNK + c) * 64 + t] = acs[t];
    for (int i = 0; i < 16; i++) {
        int e = t + i * 256;
        int l = e >> 6, col = e & 63;
        int row = b * SEQ + c * 64 + l;
        Xd[l][col] = xs[(size_t)row * DINNER + hh * 64 + col] * dts[l];
        Bw[l][col] = Bm[row * DSTATE + col] * expf(alast - acs[l]);
    }
    __syncthreads();
    // states[p][n] = sum_l Xd[l][p] * Bw[l][n]     (4x4 micro-tile per thread)
    int tx = t & 15, ty = t >> 4;
    float acc[4][4] = {};
    for (int l = 0; l < 64; l++) {
        float a0 = Xd[l][ty*4+0], a1 = Xd[l][ty*4+1],
              a2 = Xd[l][ty*4+2], a3 = Xd[l][ty*4+3];
        float b0 = Bw[l][tx*4+0], b1 = Bw[l][tx*4+1],
              b2 = Bw[l][tx*4+2], b3 = Bw[l][tx*4+3];
        acc[0][0]+=a0*b0; acc[0][1]+=a0*b1; acc[0][2]+=a0*b2; acc[0][3]+=a0*b3;
        acc[1][0]+=a1*b0; acc[1][1]+=a1*b1; acc[1][2]+=a1*b2; acc[1][3]+=a1*b3;
        acc[2][0]+=a2*b0; acc[2][1]+=a2*b1; acc[2][2]+=a2*b2; acc[2][3]+=a2*b3;
        acc[3][0]+=a3*b0; acc[3][1]+=a3*b1; acc[3][2]+=a3*b2; acc[3][3]+=a3*b3;
    }
    float* outp = states + (size_t)blk * 4096;
    for (int i = 0; i < 4; i++)
        for (int j = 0; j < 4; j++)
            outp[(ty*4+i) * 64 + tx*4 + j] = acc[i][j];
}

// ------------------------------------------- SSD: inter-chunk sequential scan
// block = b*NHEADS + h; in-place: slot c becomes the ENTERING state for chunk c
__global__ __launch_bounds__(256) void ssd_scan_kernel(
    float* __restrict__ states, const float* __restrict__ Acs_g) {
    int blk = blockIdx.x;
    int hh = blk % NHEADS, b = blk / NHEADS;
    int t = threadIdx.x;
    float S[16];
    #pragma unroll
    for (int i = 0; i < 16; i++) S[i] = 0.f;
    for (int c = 0; c < NCHUNK; c++) {
        float dec = expf(Acs_g[((b * NHEADS + hh) * NCHUNK + c) * 64 + 63]);
        float* ptr = states + (size_t)((b * NCHUNK + c) * NHEADS + hh) * 4096 + t * 16;
        #pragma unroll
        for (int i = 0; i < 16; i++) {
            float local = ptr[i];
            ptr[i] = S[i];
            S[i] = dec * S[i] + local;
        }
    }
}

// --------------------------------- SSD: Y = Y_diag + Y_off + D*X   per chunk
__global__ __launch_bounds__(256) void ssd_out_kernel(
    const float* __restrict__ xs, const float* __restrict__ Bm,
    const float* __restrict__ Cm, const float* __restrict__ dtb,
    const float* __restrict__ states, const float* __restrict__ Acs_g,
    const float* __restrict__ Dv, float* __restrict__ Y) {
    int blk = blockIdx.x;
    int hh = blk % NHEADS;
    int bc = blk / NHEADS;
    int c = bc % NCHUNK, b = bc / NCHUNK;
    __shared__ float Cs[64][65];
    __shared__ float Bt[64][65];     // B transposed: Bt[n][s]
    __shared__ float Xd[64][64];
    __shared__ float St[64][65];     // S_in transposed: St[n][p]
    __shared__ float G[64][65];
    __shared__ float acs[64];
    __shared__ float dts[64];
    int t = threadIdx.x;
    if (t < 64) {
        acs[t] = Acs_g[((b * NHEADS + hh) * NCHUNK + c) * 64 + t];
        dts[t] = dtb[(b * SEQ + c * 64 + t) * NHEADS + hh];
    }
    __syncthreads();
    for (int i = 0; i < 16; i++) {
        int e = t + i * 256;
        int l = e >> 6, n = e & 63;
        int row = b * SEQ + c * 64 + l;
        Cs[l][n] = Cm[row * DSTATE + n];
        Bt[n][l] = Bm[row * DSTATE + n];
        St[n][l] = states[(size_t)blk * 4096 + l * 64 + n];   // l plays role of p
        Xd[l][n] = xs[(size_t)row * DINNER + hh * 64 + n] * dts[l];
    }
    __syncthreads();
    int tx = t & 15, ty = t >> 4;
    // ---- G[l][s] = (C_l . B_s) * exp(acs[l]-acs[s]) for s<=l
    {
        float g[4][4] = {};
        for (int n = 0; n < 64; n++) {
            float a0 = Cs[ty*4+0][n], a1 = Cs[ty*4+1][n],
                  a2 = Cs[ty*4+2][n], a3 = Cs[ty*4+3][n];
            float b0 = Bt[n][tx*4+0], b1 = Bt[n][tx*4+1],
                  b2 = Bt[n][tx*4+2], b3 = Bt[n][tx*4+3];
            g[0][0]+=a0*b0; g[0][1]+=a0*b1; g[0][2]+=a0*b2; g[0][3]+=a0*b3;
            g[1][0]+=a1*b0; g[1][1]+=a1*b1; g[1][2]+=a1*b2; g[1][3]+=a1*b3;
            g[2][0]+=a2*b0; g[2][1]+=a2*b1; g[2][2]+=a2*b2; g[2][3]+=a2*b3;
            g[3][0]+=a3*b0; g[3][1]+=a3*b1; g[3][2]+=a3*b2; g[3][3]+=a3*b3;
        }
        for (int i = 0; i < 4; i++) {
            int l = ty*4 + i;
            for (int j = 0; j < 4; j++) {
                int s = tx*4 + j;
                G[l][s] = (s <= l) ? g[i][j] * expf(acs[l] - acs[s]) : 0.f;
            }
        }
    }
    __syncthreads();
    // ---- Y[l][p] = sum_s G[l][s]*Xd[s][p] + exp(acs[l]) * sum_n Cs[l][n]*St[n][p] + D*X
    {
        float yd[4][4] = {}, yo[4][4] = {};
        for (int s = 0; s < 64; s++) {
            float a0 = G[ty*4+0][s], a1 = G[ty*4+1][s],
                  a2 = G[ty*4+2][s], a3 = G[ty*4+3][s];
            float x0 = Xd[s][tx*4+0], x1 = Xd[s][tx*4+1],
                  x2 = Xd[s][tx*4+2], x3 = Xd[s][tx*4+3];
            yd[0][0]+=a0*x0; yd[0][1]+=a0*x1; yd[0][2]+=a0*x2; yd[0][3]+=a0*x3;
            yd[1][0]+=a1*x0; yd[1][1]+=a1*x1; yd[1][2]+=a1*x2; yd[1][3]+=a1*x3;
            yd[2][0]+=a2*x0; yd[2][1]+=a2*x1; yd[2][2]+=a2*x2; yd[2][3]+=a2*x3;
            yd[3][0]+=a3*x0; yd[3][1]+=a3*x1; yd[3][2]+=a3*x2; yd[3][3]+=a3*x3;
        }
        for (int n = 0; n < 64; n++) {
            float a0 = Cs[ty*4+0][n], a1 = Cs[ty*4+1][n],
                  a2 = Cs[ty*4+2][n], a3 = Cs[ty*4+3][n];
            float s0 = St[n][tx*4+0], s1 = St[n][tx*4+1],
                  s2 = St[n][tx*4+2], s3 = St[n][tx*4+3];
            yo[0][0]+=a0*s0; yo[0][1]+=a0*s1; yo[0][2]+=a0*s2; yo[0][3]+=a0*s3;
            yo[1][0]+=a1*s0; yo[1][1]+=a1*s1; yo[1][2]+=a1*s2; yo[1][3]+=a1*s3;
            yo[2][0]+=a2*s0; yo[2][1]+=a2*s1; yo[2][2]+=a2*s2; yo[2][3]+=a2*s3;
            yo[3][0]+=a3*s0; yo[3][1]+=a3*s1; yo[3][2]+=a3*s2; yo[3][3]+=a3*s3;
        }
        float Dh = Dv[hh];
        for (int i = 0; i < 4; i++) {
            int l = ty*4 + i;
            int row = b * SEQ + c * 64 + l;
            float el = expf(acs[l]);
            for (int j = 0; j < 4; j++) {
                int p = tx*4 + j;
                float xraw = xs[(size_t)row * DINNER + hh * 64 + p];
                Y[(size_t)row * DINNER + hh * 64 + p] = yd[i][j] + el * yo[i][j] + Dh * xraw;
            }
        }
    }
}

// --------------------------------------------------- gated RMSNorm (z-gate)
__global__ __launch_bounds__(256) void rms_kernel(
    const float* __restrict__ Y, const float* __restrict__ zx,
    const float* __restrict__ nw, float* __restrict__ yn) {
    int row = blockIdx.x;
    const float* yr = Y + (size_t)row * DINNER;
    const float* zr = zx + (size_t)row * DINPROJ;   // z = cols [0, 2048)
    float* outr = yn + (size_t)row * DINNER;
    int t = threadIdx.x;
    float vals[8];
    float ss = 0.f;
    #pragma unroll
    for (int i = 0; i < 8; i++) {
        int idx = t + i * 256;
        float z = zr[idx];
        float v = yr[idx] * (z / (1.f + expf(-z)));
        vals[i] = v;
        ss += v * v;
    }
    for (int o = 32; o > 0; o >>= 1) ss += __shfl_down(ss, o);
    __shared__ float red[4];
    int wid = t >> 6, lane = t & 63;
    if (lane == 0) red[wid] = ss;
    __syncthreads();
    if (t == 0) { float a = 0; for (int i = 0; i < 4; i++) a += red[i]; red[0] = a; }
    __syncthreads();
    float r = rsqrtf(red[0] * (1.f / DINNER) + EPSF);
    #pragma unroll
    for (int i = 0; i < 8; i++) {
        int idx = t + i * 256;
        outr[idx] = vals[i] * r * nw[idx];
    }
}

// ---------------------------------------------------------------------------
extern "C" void kernel_launch(void* const* d_in, const int* in_sizes, int n_in,
                              void* d_out, int out_size, void* d_ws, size_t ws_size,
                              hipStream_t stream) {
    const float* x          = (const float*)d_in[0];
    const float* ln_w       = (const float*)d_in[1];
    const float* ln_b       = (const float*)d_in[2];
    const float* in_proj_w  = (const float*)d_in[3];
    const float* conv_w     = (const float*)d_in[4];
    const float* conv_b     = (const float*)d_in[5];
    const float* dt_bias    = (const float*)d_in[6];
    const float* A_log      = (const float*)d_in[7];
    const float* Dv         = (const float*)d_in[8];
    const float* norm_w     = (const float*)d_in[9];
    const float* out_proj_w = (const float*)d_in[10];
    float* out = (float*)d_out;

    float* ws = (float*)d_ws;
    size_t off = 0;
    float* h_buf  = ws + off; off += (size_t)4096 * DMODEL;        // 4.19M
    float* zx     = ws + off; off += (size_t)4096 * DINPROJ;       // 17.4M
    float* xs     = ws + off; off += (size_t)4096 * DINNER;        // 8.39M
    float* states = ws + off; off += (size_t)2048 * 4096;          // 8.39M
    float* Yb     = ws + off; off += (size_t)4096 * DINNER;        // 8.39M
    // h_buf is dead after GEMM1 -> reuse for small buffers
    float* Bm  = h_buf;                    // 4096*64
    float* Cm  = h_buf + 262144;           // 4096*64
    float* dtb = h_buf + 524288;           // 4096*32
    float* Acs = h_buf + 655360;           // 2*32*32*64
    float* yn  = xs;                       // xs dead after ssd_out

    ln_kernel<<<BATCH * SEQ, 256, 0, stream>>>(x, ln_w, ln_b, h_buf);

    dim3 g1((DINPROJ + 63) / 64, (BATCH * SEQ) / 64);
    gemm64_kernel<<<g1, 256, 0, stream>>>(h_buf, in_proj_w, zx,
                                          BATCH * SEQ, DINPROJ, DMODEL, nullptr);

    conv_kernel<<<(BATCH * SEQ * CONVDIM) / 256, 256, 0, stream>>>(
        zx, conv_w, conv_b, xs, Bm, Cm);

    dt_kernel<<<(BATCH * SEQ * NHEADS) / 256, 256, 0, stream>>>(zx, dt_bias, dtb);

    ssd_states_kernel<<<BATCH * NCHUNK * NHEADS, 256, 0, stream>>>(
        xs, Bm, dtb, A_log, states, Acs);

    ssd_scan_kernel<<<BATCH * NHEADS, 256, 0, stream>>>(states, Acs);

    ssd_out_kernel<<<BATCH * NCHUNK * NHEADS, 256, 0, stream>>>(
        xs, Bm, Cm, dtb, states, Acs, Dv, Yb);

    rms_kernel<<<BATCH * SEQ, 256, 0, stream>>>(Yb, zx, norm_w, yn);

    dim3 g2(DMODEL / 64, (BATCH * SEQ) / 64);
    gemm64_kernel<<<g2, 256, 0, stream>>>(yn, out_proj_w, out,
                                          BATCH * SEQ, DMODEL, DINNER, x);
}

// Round 2
// 360.519 us; speedup vs baseline: 2.8297x; 2.8297x over previous
//
#include <hip/hip_runtime.h>
#include <hip/hip_bf16.h>

#define BATCH   2
#define SEQ     2048
#define DMODEL  1024
#define DINNER  2048
#define DSTATE  64
#define NHEADS  32
#define HEADDIM 64
#define CONVDIM 2176
#define DINPROJ 4256
#define NPAD    4352        // DINPROJ padded to 34*128 for the MFMA GEMM
#define NCHUNK  32          // SEQ / 64
#define EPSF    1e-5f

typedef __bf16 bf16;
typedef bf16  bf16x8 __attribute__((ext_vector_type(8)));
typedef float f32x4  __attribute__((ext_vector_type(4)));

__device__ __forceinline__ void gll16(const bf16* g, bf16* l) {
    __builtin_amdgcn_global_load_lds(
        (const __attribute__((address_space(1))) void*)g,
        (__attribute__((address_space(3))) void*)l, 16, 0, 0);
}

// ---------------------------------------------------------------- LayerNorm -> bf16
__global__ __launch_bounds__(256) void ln_kernel(
    const float* __restrict__ x, const float* __restrict__ w,
    const float* __restrict__ bv, bf16* __restrict__ h) {
    int row = blockIdx.x;                    // 4096 rows
    const float* xr = x + (size_t)row * DMODEL;
    bf16* hr = h + (size_t)row * DMODEL;
    int t = threadIdx.x;
    float4 v = ((const float4*)xr)[t];
    float s  = v.x + v.y + v.z + v.w;
    float ss = v.x*v.x + v.y*v.y + v.z*v.z + v.w*v.w;
    for (int o = 32; o > 0; o >>= 1) { s += __shfl_down(s, o); ss += __shfl_down(ss, o); }
    __shared__ float red[2][4];
    int wid = t >> 6, lane = t & 63;
    if (lane == 0) { red[0][wid] = s; red[1][wid] = ss; }
    __syncthreads();
    if (t == 0) {
        float a = 0, b2 = 0;
        for (int i = 0; i < 4; i++) { a += red[0][i]; b2 += red[1][i]; }
        red[0][0] = a; red[1][0] = b2;
    }
    __syncthreads();
    float mean = red[0][0] * (1.f / DMODEL);
    float var  = red[1][0] * (1.f / DMODEL) - mean * mean;
    float rstd = rsqrtf(var + EPSF);
    for (int i = t; i < DMODEL; i += 256)
        hr[i] = (bf16)((xr[i] - mean) * rstd * w[i] + bv[i]);
}

// -------------------------------------------- weight transpose + bf16 cast (+pad)
// W[K][N] fp32 -> Bt[NP][K] bf16, rows n >= N zero-filled.
__global__ __launch_bounds__(256) void cvt_w_kernel(
    const float* __restrict__ W, bf16* __restrict__ Bt, int K, int N, int NP) {
    __shared__ float sm[32][33];
    int n0 = blockIdx.x * 32, k0 = blockIdx.y * 32;
    int tx = threadIdx.x & 31, ty = threadIdx.x >> 5;   // 32 x 8
    for (int i = 0; i < 4; i++) {
        int k = k0 + ty + i * 8, n = n0 + tx;
        sm[ty + i * 8][tx] = (n < N) ? W[(size_t)k * N + n] : 0.f;
    }
    __syncthreads();
    for (int i = 0; i < 4; i++) {
        int n = n0 + ty + i * 8, k = k0 + tx;
        if (n < NP) Bt[(size_t)n * K + k] = (bf16)sm[tx][ty + i * 8];
    }
}

// ---------------------------------------------------------------- bf16 MFMA GEMM
// C[M][N] (fp32) = A[M][K] (bf16) @ Bt[N][K]^T (bf16) (+resid). 128x128 tile, BK=32.
__global__ __launch_bounds__(256) void gemm_bf16_kernel(
    const bf16* __restrict__ A, const bf16* __restrict__ Bt,
    float* __restrict__ C, int M, int N, int K,
    const float* __restrict__ resid) {
    __shared__ __align__(16) bf16 sA[128 * 32];
    __shared__ __align__(16) bf16 sB[128 * 32];
    int t = threadIdx.x;
    int lane = t & 63, w = t >> 6;
    int m0 = blockIdx.y * 128, n0 = blockIdx.x * 128;
    int wm = w >> 1, wn = w & 1;                 // wave -> 64x64 quadrant
    f32x4 acc[4][4] = {};
    // staging geometry: issue i, wave w covers LDS bytes [(i*4+w)*1024, +1024)
    int srow[2], scol;
    scol = (lane & 3) * 8;
    srow[0] = w * 16 + (lane >> 2);
    srow[1] = 64 + srow[0];
    int fr = lane & 15;                          // fragment row
    int fc = (lane >> 4) * 8;                    // fragment k-offset
    for (int k0 = 0; k0 < K; k0 += 32) {
        #pragma unroll
        for (int i = 0; i < 2; i++) {
            gll16(&A[(size_t)(m0 + srow[i]) * K + k0 + scol], &sA[i * 2048 + w * 512]);
            gll16(&Bt[(size_t)(n0 + srow[i]) * K + k0 + scol], &sB[i * 2048 + w * 512]);
        }
        __syncthreads();                         // drains vmcnt, LDS tiles ready
        bf16x8 af[4], bfr[4];
        #pragma unroll
        for (int i = 0; i < 4; i++)
            af[i] = *(const bf16x8*)&sA[(wm * 64 + i * 16 + fr) * 32 + fc];
        #pragma unroll
        for (int j = 0; j < 4; j++)
            bfr[j] = *(const bf16x8*)&sB[(wn * 64 + j * 16 + fr) * 32 + fc];
        #pragma unroll
        for (int i = 0; i < 4; i++)
            #pragma unroll
            for (int j = 0; j < 4; j++)
                acc[i][j] = __builtin_amdgcn_mfma_f32_16x16x32_bf16(
                    af[i], bfr[j], acc[i][j], 0, 0, 0);
        __syncthreads();                         // all reads done before next stage
    }
    // C/D layout: col = lane&15, row = (lane>>4)*4 + r
    #pragma unroll
    for (int i = 0; i < 4; i++) {
        #pragma unroll
        for (int j = 0; j < 4; j++) {
            int col = n0 + wn * 64 + j * 16 + (lane & 15);
            #pragma unroll
            for (int r = 0; r < 4; r++) {
                int row = m0 + wm * 64 + i * 16 + (lane >> 4) * 4 + r;
                float v = acc[i][j][r];
                if (resid) v += resid[(size_t)row * N + col];
                C[(size_t)row * N + col] = v;
            }
        }
    }
}

// ------------------------------------------------- causal depthwise conv + SiLU
__global__ __launch_bounds__(256) void conv_kernel(
    const float* __restrict__ zx, const float* __restrict__ cw,
    const float* __restrict__ cb, float* __restrict__ xs,
    float* __restrict__ Bm, float* __restrict__ Cm) {
    int idx = blockIdx.x * 256 + threadIdx.x;        // b*l*CONVDIM
    int ch = idx % CONVDIM;
    int bl = idx / CONVDIM;
    int b = bl / SEQ, tt = bl % SEQ;
    float acc = cb[ch];
    #pragma unroll
    for (int k = 0; k < 4; k++) {
        int tp = tt - 3 + k;
        if (tp >= 0)
            acc += zx[(size_t)(b * SEQ + tp) * NPAD + DINNER + ch] * cw[ch * 4 + k];
    }
    float s = acc / (1.f + expf(-acc));
    if (ch < DINNER)              xs[(size_t)bl * DINNER + ch] = s;
    else if (ch < DINNER+DSTATE)  Bm[bl * DSTATE + (ch - DINNER)] = s;
    else                          Cm[bl * DSTATE + (ch - DINNER - DSTATE)] = s;
}

// ---------------------------------------------------------------- dt softplus
__global__ __launch_bounds__(256) void dt_kernel(
    const float* __restrict__ zx, const float* __restrict__ dt_bias,
    float* __restrict__ dtb) {
    int idx = blockIdx.x * 256 + threadIdx.x;        // b*l*NHEADS
    int hh = idx % NHEADS;
    int bl = idx / NHEADS;
    float v = zx[(size_t)bl * NPAD + (DINNER + CONVDIM) + hh] + dt_bias[hh];
    dtb[idx] = (v > 20.f) ? v : log1pf(expf(v));
}

// ----------------------------------------- SSD: per-chunk local states + A_cs
__global__ __launch_bounds__(256) void ssd_states_kernel(
    const float* __restrict__ xs, const float* __restrict__ Bm,
    const float* __restrict__ dtb, const float* __restrict__ A_log,
    float* __restrict__ states, float* __restrict__ Acs_g) {
    int blk = blockIdx.x;
    int hh = blk % NHEADS;
    int bc = blk / NHEADS;
    int c = bc % NCHUNK, b = bc / NCHUNK;
    __shared__ float Xd[64][64];
    __shared__ float Bw[64][64];
    __shared__ float dts[64];
    __shared__ float acs[64];
    int t = threadIdx.x;
    float Ah = -expf(A_log[hh]);
    if (t < 64) {                                // wave 0: load + parallel scan
        float dv = dtb[(b * SEQ + c * 64 + t) * NHEADS + hh];
        dts[t] = dv;
        float v = dv * Ah;
        #pragma unroll
        for (int o = 1; o < 64; o <<= 1) {
            float p = __shfl_up(v, o);
            if (t >= o) v += p;
        }
        acs[t] = v;
    }
    __syncthreads();
    float alast = acs[63];
    if (t < 64)
        Acs_g[((b * NHEADS + hh) * NCHUNK + c) * 64 + t] = acs[t];
    for (int i = 0; i < 16; i++) {
        int e = t + i * 256;
        int l = e >> 6, col = e & 63;
        int row = b * SEQ + c * 64 + l;
        Xd[l][col] = xs[(size_t)row * DINNER + hh * 64 + col] * dts[l];
        Bw[l][col] = Bm[row * DSTATE + col] * expf(alast - acs[l]);
    }
    __syncthreads();
    int tx = t & 15, ty = t >> 4;
    float acc[4][4] = {};
    for (int l = 0; l < 64; l++) {
        float a0 = Xd[l][ty*4+0], a1 = Xd[l][ty*4+1],
              a2 = Xd[l][ty*4+2], a3 = Xd[l][ty*4+3];
        float b0 = Bw[l][tx*4+0], b1 = Bw[l][tx*4+1],
              b2 = Bw[l][tx*4+2], b3 = Bw[l][tx*4+3];
        acc[0][0]+=a0*b0; acc[0][1]+=a0*b1; acc[0][2]+=a0*b2; acc[0][3]+=a0*b3;
        acc[1][0]+=a1*b0; acc[1][1]+=a1*b1; acc[1][2]+=a1*b2; acc[1][3]+=a1*b3;
        acc[2][0]+=a2*b0; acc[2][1]+=a2*b1; acc[2][2]+=a2*b2; acc[2][3]+=a2*b3;
        acc[3][0]+=a3*b0; acc[3][1]+=a3*b1; acc[3][2]+=a3*b2; acc[3][3]+=a3*b3;
    }
    float* outp = states + (size_t)blk * 4096;
    for (int i = 0; i < 4; i++)
        for (int j = 0; j < 4; j++)
            outp[(ty*4+i) * 64 + tx*4 + j] = acc[i][j];
}

// ------------------------------------------- SSD: inter-chunk sequential scan
__global__ __launch_bounds__(256) void ssd_scan_kernel(
    float* __restrict__ states, const float* __restrict__ Acs_g) {
    int blk = blockIdx.x;
    int hh = blk % NHEADS, b = blk / NHEADS;
    int t = threadIdx.x;
    float S[16];
    #pragma unroll
    for (int i = 0; i < 16; i++) S[i] = 0.f;
    for (int c = 0; c < NCHUNK; c++) {
        float dec = expf(Acs_g[((b * NHEADS + hh) * NCHUNK + c) * 64 + 63]);
        float* ptr = states + (size_t)((b * NCHUNK + c) * NHEADS + hh) * 4096 + t * 16;
        #pragma unroll
        for (int i = 0; i < 16; i++) {
            float local = ptr[i];
            ptr[i] = S[i];
            S[i] = dec * S[i] + local;
        }
    }
}

// --------------------------------- SSD: Y = Y_diag + Y_off + D*X   per chunk
__global__ __launch_bounds__(256) void ssd_out_kernel(
    const float* __restrict__ xs, const float* __restrict__ Bm,
    const float* __restrict__ Cm, const float* __restrict__ dtb,
    const float* __restrict__ states, const float* __restrict__ Acs_g,
    const float* __restrict__ Dv, float* __restrict__ Y) {
    int blk = blockIdx.x;
    int hh = blk % NHEADS;
    int bc = blk / NHEADS;
    int c = bc % NCHUNK, b = bc / NCHUNK;
    __shared__ float Cs[64][65];
    __shared__ float Bt[64][65];
    __shared__ float Xd[64][64];
    __shared__ float St[64][65];
    __shared__ float G[64][65];
    __shared__ float acs[64];
    __shared__ float dts[64];
    int t = threadIdx.x;
    if (t < 64) {
        acs[t] = Acs_g[((b * NHEADS + hh) * NCHUNK + c) * 64 + t];
        dts[t] = dtb[(b * SEQ + c * 64 + t) * NHEADS + hh];
    }
    __syncthreads();
    for (int i = 0; i < 16; i++) {
        int e = t + i * 256;
        int l = e >> 6, n = e & 63;
        int row = b * SEQ + c * 64 + l;
        Cs[l][n] = Cm[row * DSTATE + n];
        Bt[n][l] = Bm[row * DSTATE + n];
        St[n][l] = states[(size_t)blk * 4096 + l * 64 + n];
        Xd[l][n] = xs[(size_t)row * DINNER + hh * 64 + n] * dts[l];
    }
    __syncthreads();
    int tx = t & 15, ty = t >> 4;
    {
        float g[4][4] = {};
        for (int n = 0; n < 64; n++) {
            float a0 = Cs[ty*4+0][n], a1 = Cs[ty*4+1][n],
                  a2 = Cs[ty*4+2][n], a3 = Cs[ty*4+3][n];
            float b0 = Bt[n][tx*4+0], b1 = Bt[n][tx*4+1],
                  b2 = Bt[n][tx*4+2], b3 = Bt[n][tx*4+3];
            g[0][0]+=a0*b0; g[0][1]+=a0*b1; g[0][2]+=a0*b2; g[0][3]+=a0*b3;
            g[1][0]+=a1*b0; g[1][1]+=a1*b1; g[1][2]+=a1*b2; g[1][3]+=a1*b3;
            g[2][0]+=a2*b0; g[2][1]+=a2*b1; g[2][2]+=a2*b2; g[2][3]+=a2*b3;
            g[3][0]+=a3*b0; g[3][1]+=a3*b1; g[3][2]+=a3*b2; g[3][3]+=a3*b3;
        }
        for (int i = 0; i < 4; i++) {
            int l = ty*4 + i;
            for (int j = 0; j < 4; j++) {
                int s = tx*4 + j;
                G[l][s] = (s <= l) ? g[i][j] * expf(acs[l] - acs[s]) : 0.f;
            }
        }
    }
    __syncthreads();
    {
        float yd[4][4] = {}, yo[4][4] = {};
        for (int s = 0; s < 64; s++) {
            float a0 = G[ty*4+0][s], a1 = G[ty*4+1][s],
                  a2 = G[ty*4+2][s], a3 = G[ty*4+3][s];
            float x0 = Xd[s][tx*4+0], x1 = Xd[s][tx*4+1],
                  x2 = Xd[s][tx*4+2], x3 = Xd[s][tx*4+3];
            yd[0][0]+=a0*x0; yd[0][1]+=a0*x1; yd[0][2]+=a0*x2; yd[0][3]+=a0*x3;
            yd[1][0]+=a1*x0; yd[1][1]+=a1*x1; yd[1][2]+=a1*x2; yd[1][3]+=a1*x3;
            yd[2][0]+=a2*x0; yd[2][1]+=a2*x1; yd[2][2]+=a2*x2; yd[2][3]+=a2*x3;
            yd[3][0]+=a3*x0; yd[3][1]+=a3*x1; yd[3][2]+=a3*x2; yd[3][3]+=a3*x3;
        }
        for (int n = 0; n < 64; n++) {
            float a0 = Cs[ty*4+0][n], a1 = Cs[ty*4+1][n],
                  a2 = Cs[ty*4+2][n], a3 = Cs[ty*4+3][n];
            float s0 = St[n][tx*4+0], s1 = St[n][tx*4+1],
                  s2 = St[n][tx*4+2], s3 = St[n][tx*4+3];
            yo[0][0]+=a0*s0; yo[0][1]+=a0*s1; yo[0][2]+=a0*s2; yo[0][3]+=a0*s3;
            yo[1][0]+=a1*s0; yo[1][1]+=a1*s1; yo[1][2]+=a1*s2; yo[1][3]+=a1*s3;
            yo[2][0]+=a2*s0; yo[2][1]+=a2*s1; yo[2][2]+=a2*s2; yo[2][3]+=a2*s3;
            yo[3][0]+=a3*s0; yo[3][1]+=a3*s1; yo[3][2]+=a3*s2; yo[3][3]+=a3*s3;
        }
        float Dh = Dv[hh];
        for (int i = 0; i < 4; i++) {
            int l = ty*4 + i;
            int row = b * SEQ + c * 64 + l;
            float el = expf(acs[l]);
            for (int j = 0; j < 4; j++) {
                int p = tx*4 + j;
                float xraw = xs[(size_t)row * DINNER + hh * 64 + p];
                Y[(size_t)row * DINNER + hh * 64 + p] = yd[i][j] + el * yo[i][j] + Dh * xraw;
            }
        }
    }
}

// --------------------------------------------------- gated RMSNorm -> bf16
__global__ __launch_bounds__(256) void rms_kernel(
    const float* __restrict__ Y, const float* __restrict__ zx,
    const float* __restrict__ nw, bf16* __restrict__ yn) {
    int row = blockIdx.x;
    const float* yr = Y + (size_t)row * DINNER;
    const float* zr = zx + (size_t)row * NPAD;      // z = cols [0, 2048)
    bf16* outr = yn + (size_t)row * DINNER;
    int t = threadIdx.x;
    float vals[8];
    float ss = 0.f;
    #pragma unroll
    for (int i = 0; i < 8; i++) {
        int idx = t + i * 256;
        float z = zr[idx];
        float v = yr[idx] * (z / (1.f + expf(-z)));
        vals[i] = v;
        ss += v * v;
    }
    for (int o = 32; o > 0; o >>= 1) ss += __shfl_down(ss, o);
    __shared__ float red[4];
    int wid = t >> 6, lane = t & 63;
    if (lane == 0) red[wid] = ss;
    __syncthreads();
    if (t == 0) { float a = 0; for (int i = 0; i < 4; i++) a += red[i]; red[0] = a; }
    __syncthreads();
    float r = rsqrtf(red[0] * (1.f / DINNER) + EPSF);
    #pragma unroll
    for (int i = 0; i < 8; i++) {
        int idx = t + i * 256;
        outr[idx] = (bf16)(vals[i] * r * nw[idx]);
    }
}

// ---------------------------------------------------------------------------
extern "C" void kernel_launch(void* const* d_in, const int* in_sizes, int n_in,
                              void* d_out, int out_size, void* d_ws, size_t ws_size,
                              hipStream_t stream) {
    const float* x          = (const float*)d_in[0];
    const float* ln_w       = (const float*)d_in[1];
    const float* ln_b       = (const float*)d_in[2];
    const float* in_proj_w  = (const float*)d_in[3];
    const float* conv_w     = (const float*)d_in[4];
    const float* conv_b     = (const float*)d_in[5];
    const float* dt_bias    = (const float*)d_in[6];
    const float* A_log      = (const float*)d_in[7];
    const float* Dv         = (const float*)d_in[8];
    const float* norm_w     = (const float*)d_in[9];
    const float* out_proj_w = (const float*)d_in[10];
    float* out = (float*)d_out;

    char* ws = (char*)d_ws;
    size_t off = 0;
    auto alloc = [&](size_t bytes) { char* p = ws + off; off += (bytes + 255) & ~(size_t)255; return p; };
    bf16*  h_bf  = (bf16*) alloc((size_t)4096 * DMODEL * 2);     //  8.4 MB
    float* zx    = (float*)alloc((size_t)4096 * NPAD * 4);       // 71.3 MB
    float* xs    = (float*)alloc((size_t)4096 * DINNER * 4);     // 33.6 MB
    float* states= (float*)alloc((size_t)2048 * 4096 * 4);       // 33.6 MB
    float* Yb    = (float*)alloc((size_t)4096 * DINNER * 4);     // 33.6 MB
    bf16*  Bt1   = (bf16*) alloc((size_t)NPAD * DMODEL * 2);     //  8.9 MB
    float* dtb   = (float*)alloc((size_t)4096 * NHEADS * 4);     //  0.5 MB
    float* Acs   = (float*)alloc((size_t)2 * NHEADS * NCHUNK * 64 * 4);
    // h_bf dead after GEMM1 -> reuse for Bm/Cm (each 4096*64 fp32 = 1 MB)
    float* Bm = (float*)h_bf;
    float* Cm = (float*)(h_bf + (size_t)2 * 1024 * 1024);
    // Bt1 dead after GEMM1 -> reuse for Bt2 (1024*2048 bf16 = 4.2 MB)
    bf16* Bt2 = Bt1;
    // xs dead after ssd_out -> reuse for yn (bf16)
    bf16* yn = (bf16*)xs;

    ln_kernel<<<BATCH * SEQ, 256, 0, stream>>>(x, ln_w, ln_b, h_bf);

    {   // in_proj_w (1024 x 4256) -> Bt1 [4352][1024]
        dim3 g(NPAD / 32, DMODEL / 32);
        cvt_w_kernel<<<g, 256, 0, stream>>>(in_proj_w, Bt1, DMODEL, DINPROJ, NPAD);
    }
    {   // zx = h @ in_proj_w   (4096 x 4352 x 1024)
        dim3 g(NPAD / 128, (BATCH * SEQ) / 128);
        gemm_bf16_kernel<<<g, 256, 0, stream>>>(h_bf, Bt1, zx,
                                                BATCH * SEQ, NPAD, DMODEL, nullptr);
    }

    conv_kernel<<<(BATCH * SEQ * CONVDIM) / 256, 256, 0, stream>>>(
        zx, conv_w, conv_b, xs, Bm, Cm);

    dt_kernel<<<(BATCH * SEQ * NHEADS) / 256, 256, 0, stream>>>(zx, dt_bias, dtb);

    ssd_states_kernel<<<BATCH * NCHUNK * NHEADS, 256, 0, stream>>>(
        xs, Bm, dtb, A_log, states, Acs);

    ssd_scan_kernel<<<BATCH * NHEADS, 256, 0, stream>>>(states, Acs);

    ssd_out_kernel<<<BATCH * NCHUNK * NHEADS, 256, 0, stream>>>(
        xs, Bm, Cm, dtb, states, Acs, Dv, Yb);

    rms_kernel<<<BATCH * SEQ, 256, 0, stream>>>(Yb, zx, norm_w, yn);

    {   // out_proj_w (2048 x 1024) -> Bt2 [1024][2048]
        dim3 g(DMODEL / 32, DINNER / 32);
        cvt_w_kernel<<<g, 256, 0, stream>>>(out_proj_w, Bt2, DINNER, DMODEL, DMODEL);
    }
    {   // out = yn @ out_proj_w + x   (4096 x 1024 x 2048)
        dim3 g(DMODEL / 128, (BATCH * SEQ) / 128);
        gemm_bf16_kernel<<<g, 256, 0, stream>>>(yn, Bt2, out,
                                                BATCH * SEQ, DMODEL, DINNER, x);
    }
}

// Round 3
// 300.749 us; speedup vs baseline: 3.3920x; 1.1987x over previous
//
#include <hip/hip_runtime.h>
#include <hip/hip_bf16.h>

#define BATCH   2
#define SEQ     2048
#define DMODEL  1024
#define DINNER  2048
#define DSTATE  64
#define NHEADS  32
#define HEADDIM 64
#define CONVDIM 2176
#define DINPROJ 4256
#define NPAD    4352        // DINPROJ padded to 34*128 for the MFMA GEMM
#define NCHUNK  32          // SEQ / 64
#define EPSF    1e-5f

typedef __bf16 bf16;
typedef bf16  bf16x8 __attribute__((ext_vector_type(8)));
typedef float f32x4  __attribute__((ext_vector_type(4)));

__device__ __forceinline__ void gll16(const bf16* g, bf16* l) {
    __builtin_amdgcn_global_load_lds(
        (const __attribute__((address_space(1))) void*)g,
        (__attribute__((address_space(3))) void*)l, 16, 0, 0);
}

// ---------------------------------------------------------------- LayerNorm -> bf16
__global__ __launch_bounds__(256) void ln_kernel(
    const float* __restrict__ x, const float* __restrict__ w,
    const float* __restrict__ bv, bf16* __restrict__ h) {
    int row = blockIdx.x;                    // 4096 rows
    const float* xr = x + (size_t)row * DMODEL;
    bf16* hr = h + (size_t)row * DMODEL;
    int t = threadIdx.x;
    float4 v = ((const float4*)xr)[t];
    float s  = v.x + v.y + v.z + v.w;
    float ss = v.x*v.x + v.y*v.y + v.z*v.z + v.w*v.w;
    for (int o = 32; o > 0; o >>= 1) { s += __shfl_down(s, o); ss += __shfl_down(ss, o); }
    __shared__ float red[2][4];
    int wid = t >> 6, lane = t & 63;
    if (lane == 0) { red[0][wid] = s; red[1][wid] = ss; }
    __syncthreads();
    if (t == 0) {
        float a = 0, b2 = 0;
        for (int i = 0; i < 4; i++) { a += red[0][i]; b2 += red[1][i]; }
        red[0][0] = a; red[1][0] = b2;
    }
    __syncthreads();
    float mean = red[0][0] * (1.f / DMODEL);
    float var  = red[1][0] * (1.f / DMODEL) - mean * mean;
    float rstd = rsqrtf(var + EPSF);
    for (int i = t; i < DMODEL; i += 256)
        hr[i] = (bf16)((xr[i] - mean) * rstd * w[i] + bv[i]);
}

// -------------------------------------------- weight transpose + bf16 cast (+pad)
__global__ __launch_bounds__(256) void cvt_w_kernel(
    const float* __restrict__ W, bf16* __restrict__ Bt, int K, int N, int NP) {
    __shared__ float sm[32][33];
    int n0 = blockIdx.x * 32, k0 = blockIdx.y * 32;
    int tx = threadIdx.x & 31, ty = threadIdx.x >> 5;   // 32 x 8
    for (int i = 0; i < 4; i++) {
        int k = k0 + ty + i * 8, n = n0 + tx;
        sm[ty + i * 8][tx] = (n < N) ? W[(size_t)k * N + n] : 0.f;
    }
    __syncthreads();
    for (int i = 0; i < 4; i++) {
        int n = n0 + ty + i * 8, k = k0 + tx;
        if (n < NP) Bt[(size_t)n * K + k] = (bf16)sm[tx][ty + i * 8];
    }
}

// ---------------------------------------------------------------- bf16 MFMA GEMM
// C[M][N] (fp32) = A[M][K] (bf16) @ Bt[N][K]^T (bf16) (+resid). 128x128 tile, BK=32.
__global__ __launch_bounds__(256) void gemm_bf16_kernel(
    const bf16* __restrict__ A, const bf16* __restrict__ Bt,
    float* __restrict__ C, int M, int N, int K,
    const float* __restrict__ resid) {
    __shared__ __align__(16) bf16 sA[128 * 32];
    __shared__ __align__(16) bf16 sB[128 * 32];
    int t = threadIdx.x;
    int lane = t & 63, w = t >> 6;
    int m0 = blockIdx.y * 128, n0 = blockIdx.x * 128;
    int wm = w >> 1, wn = w & 1;
    f32x4 acc[4][4] = {};
    int srow[2], scol;
    scol = (lane & 3) * 8;
    srow[0] = w * 16 + (lane >> 2);
    srow[1] = 64 + srow[0];
    int fr = lane & 15;
    int fc = (lane >> 4) * 8;
    for (int k0 = 0; k0 < K; k0 += 32) {
        #pragma unroll
        for (int i = 0; i < 2; i++) {
            gll16(&A[(size_t)(m0 + srow[i]) * K + k0 + scol], &sA[i * 2048 + w * 512]);
            gll16(&Bt[(size_t)(n0 + srow[i]) * K + k0 + scol], &sB[i * 2048 + w * 512]);
        }
        __syncthreads();
        bf16x8 af[4], bfr[4];
        #pragma unroll
        for (int i = 0; i < 4; i++)
            af[i] = *(const bf16x8*)&sA[(wm * 64 + i * 16 + fr) * 32 + fc];
        #pragma unroll
        for (int j = 0; j < 4; j++)
            bfr[j] = *(const bf16x8*)&sB[(wn * 64 + j * 16 + fr) * 32 + fc];
        #pragma unroll
        for (int i = 0; i < 4; i++)
            #pragma unroll
            for (int j = 0; j < 4; j++)
                acc[i][j] = __builtin_amdgcn_mfma_f32_16x16x32_bf16(
                    af[i], bfr[j], acc[i][j], 0, 0, 0);
        __syncthreads();
    }
    #pragma unroll
    for (int i = 0; i < 4; i++) {
        #pragma unroll
        for (int j = 0; j < 4; j++) {
            int col = n0 + wn * 64 + j * 16 + (lane & 15);
            #pragma unroll
            for (int r = 0; r < 4; r++) {
                int row = m0 + wm * 64 + i * 16 + (lane >> 4) * 4 + r;
                float v = acc[i][j][r];
                if (resid) v += resid[(size_t)row * N + col];
                C[(size_t)row * N + col] = v;
            }
        }
    }
}

// ------------------------------------------------- causal depthwise conv + SiLU
__global__ __launch_bounds__(256) void conv_kernel(
    const float* __restrict__ zx, const float* __restrict__ cw,
    const float* __restrict__ cb, float* __restrict__ xs,
    float* __restrict__ Bm, float* __restrict__ Cm) {
    int idx = blockIdx.x * 256 + threadIdx.x;        // b*l*CONVDIM
    int ch = idx % CONVDIM;
    int bl = idx / CONVDIM;
    int b = bl / SEQ, tt = bl % SEQ;
    float acc = cb[ch];
    #pragma unroll
    for (int k = 0; k < 4; k++) {
        int tp = tt - 3 + k;
        if (tp >= 0)
            acc += zx[(size_t)(b * SEQ + tp) * NPAD + DINNER + ch] * cw[ch * 4 + k];
    }
    float s = acc / (1.f + expf(-acc));
    if (ch < DINNER)              xs[(size_t)bl * DINNER + ch] = s;
    else if (ch < DINNER+DSTATE)  Bm[bl * DSTATE + (ch - DINNER)] = s;
    else                          Cm[bl * DSTATE + (ch - DINNER - DSTATE)] = s;
}

// ---------------------------------------------------------------- dt softplus
__global__ __launch_bounds__(256) void dt_kernel(
    const float* __restrict__ zx, const float* __restrict__ dt_bias,
    float* __restrict__ dtb) {
    int idx = blockIdx.x * 256 + threadIdx.x;        // b*l*NHEADS
    int hh = idx % NHEADS;
    int bl = idx / NHEADS;
    float v = zx[(size_t)bl * NPAD + (DINNER + CONVDIM) + hh] + dt_bias[hh];
    dtb[idx] = (v > 20.f) ? v : log1pf(expf(v));
}

// ----------------------------------------- SSD: per-chunk local states + A_cs
__global__ __launch_bounds__(256) void ssd_states_kernel(
    const float* __restrict__ xs, const float* __restrict__ Bm,
    const float* __restrict__ dtb, const float* __restrict__ A_log,
    float* __restrict__ states, float* __restrict__ Acs_g) {
    int blk = blockIdx.x;
    int hh = blk % NHEADS;
    int bc = blk / NHEADS;
    int c = bc % NCHUNK, b = bc / NCHUNK;
    __shared__ float Xd[64][64];
    __shared__ float Bw[64][64];
    __shared__ float dts[64];
    __shared__ float acs[64];
    int t = threadIdx.x;
    float Ah = -expf(A_log[hh]);
    if (t < 64) {                                // wave 0: load + parallel scan
        float dv = dtb[(b * SEQ + c * 64 + t) * NHEADS + hh];
        dts[t] = dv;
        float v = dv * Ah;
        #pragma unroll
        for (int o = 1; o < 64; o <<= 1) {
            float p = __shfl_up(v, o);
            if (t >= o) v += p;
        }
        acs[t] = v;
    }
    __syncthreads();
    float alast = acs[63];
    if (t < 64)
        Acs_g[((b * NHEADS + hh) * NCHUNK + c) * 64 + t] = acs[t];
    for (int i = 0; i < 16; i++) {
        int e = t + i * 256;
        int l = e >> 6, col = e & 63;
        int row = b * SEQ + c * 64 + l;
        Xd[l][col] = xs[(size_t)row * DINNER + hh * 64 + col] * dts[l];
        Bw[l][col] = Bm[row * DSTATE + col] * expf(alast - acs[l]);
    }
    __syncthreads();
    int tx = t & 15, ty = t >> 4;
    float acc[4][4] = {};
    for (int l = 0; l < 64; l++) {
        float a0 = Xd[l][ty*4+0], a1 = Xd[l][ty*4+1],
              a2 = Xd[l][ty*4+2], a3 = Xd[l][ty*4+3];
        float b0 = Bw[l][tx*4+0], b1 = Bw[l][tx*4+1],
              b2 = Bw[l][tx*4+2], b3 = Bw[l][tx*4+3];
        acc[0][0]+=a0*b0; acc[0][1]+=a0*b1; acc[0][2]+=a0*b2; acc[0][3]+=a0*b3;
        acc[1][0]+=a1*b0; acc[1][1]+=a1*b1; acc[1][2]+=a1*b2; acc[1][3]+=a1*b3;
        acc[2][0]+=a2*b0; acc[2][1]+=a2*b1; acc[2][2]+=a2*b2; acc[2][3]+=a2*b3;
        acc[3][0]+=a3*b0; acc[3][1]+=a3*b1; acc[3][2]+=a3*b2; acc[3][3]+=a3*b3;
    }
    float* outp = states + (size_t)blk * 4096;
    for (int i = 0; i < 4; i++)
        for (int j = 0; j < 4; j++)
            outp[(ty*4+i) * 64 + tx*4 + j] = acc[i][j];
}

// ------------------------------------------- SSD: inter-chunk sequential scan
// grid = BATCH*NHEADS*8; each block owns a 512-element slice of the 64x64 state.
// All 32 chunk-locals prefetched (independent loads); chain is 32 FMAs.
__global__ __launch_bounds__(256) void ssd_scan_kernel(
    float* __restrict__ states, const float* __restrict__ Acs_g) {
    int bid = blockIdx.x;
    int slice = bid & 7, bh = bid >> 3;
    int hh = bh % NHEADS, b = bh / NHEADS;
    int e0 = slice * 512 + threadIdx.x * 2;
    float2 loc[NCHUNK];
    float dec[NCHUNK];
    #pragma unroll
    for (int c = 0; c < NCHUNK; c++) {
        loc[c] = *(const float2*)&states[(size_t)((b*NCHUNK+c)*NHEADS+hh)*4096 + e0];
        dec[c] = expf(Acs_g[((b*NHEADS+hh)*NCHUNK + c)*64 + 63]);
    }
    float2 S = make_float2(0.f, 0.f);
    #pragma unroll
    for (int c = 0; c < NCHUNK; c++) {
        float2 l = loc[c];
        *(float2*)&states[(size_t)((b*NCHUNK+c)*NHEADS+hh)*4096 + e0] = S;
        S.x = dec[c]*S.x + l.x;
        S.y = dec[c]*S.y + l.y;
    }
}

// --------------------------------- SSD: Y = Y_diag + Y_off + D*X   per chunk
// 3 LDS tiles (52.7 KB -> 3 blocks/CU). Thread (tx,ty) owns rows l=16i+ty,
// cols 16j+tx. m1/m3 in dot form (row-major operands), m2 outer form.
__global__ __launch_bounds__(256) void ssd_out_kernel(
    const float* __restrict__ xs, const float* __restrict__ Bm,
    const float* __restrict__ Cm, const float* __restrict__ dtb,
    const float* __restrict__ states, const float* __restrict__ Acs_g,
    const float* __restrict__ Dv, float* __restrict__ Y) {
    int blk = blockIdx.x;
    int hh = blk % NHEADS;
    int bc = blk / NHEADS;
    int c = bc % NCHUNK, b = bc / NCHUNK;
    __shared__ float Cs[64][68];
    __shared__ float BG[64][68];     // B, then G' = tril(CB^T * decay) * dt
    __shared__ float Xr[64][68];     // raw X, then S_in
    __shared__ float acs[64], dts[64];
    int t = threadIdx.x;
    // T14: issue S loads to regs early; written to LDS after Xr dies.
    float4 sreg[4];
    {
        const float* sp = states + (size_t)blk * 4096 + t * 16;
        #pragma unroll
        for (int i = 0; i < 4; i++) sreg[i] = *(const float4*)&sp[i * 4];
    }
    if (t < 64) {
        acs[t] = Acs_g[((b * NHEADS + hh) * NCHUNK + c) * 64 + t];
        dts[t] = dtb[(b * SEQ + c * 64 + t) * NHEADS + hh];
    }
    {   // stage C, B, Xraw: thread t -> row t>>2, 16 floats at (t&3)*16
        int l = t >> 2, c0 = (t & 3) * 16;
        int row = b * SEQ + c * 64 + l;
        #pragma unroll
        for (int i = 0; i < 4; i++) {
            *(float4*)&Cs[l][c0 + i*4] = *(const float4*)&Cm[row * DSTATE + c0 + i*4];
            *(float4*)&BG[l][c0 + i*4] = *(const float4*)&Bm[row * DSTATE + c0 + i*4];
            *(float4*)&Xr[l][c0 + i*4] = *(const float4*)&xs[(size_t)row * DINNER + hh * 64 + c0 + i*4];
        }
    }
    __syncthreads();
    int tx = t & 15, ty = t >> 4;
    // save raw X for the D-skip before Xr is overwritten by S
    float xkeep[4][4];
    #pragma unroll
    for (int i = 0; i < 4; i++)
        #pragma unroll
        for (int j = 0; j < 4; j++)
            xkeep[i][j] = Xr[i*16 + ty][j*16 + tx];
    // m1: g[i][j] = sum_n Cs[16i+ty][n] * B[16j+tx][n]
    float g[4][4] = {};
    for (int n = 0; n < 64; n += 4) {
        float4 a[4], bb[4];
        #pragma unroll
        for (int i = 0; i < 4; i++) a[i]  = *(const float4*)&Cs[i*16 + ty][n];
        #pragma unroll
        for (int j = 0; j < 4; j++) bb[j] = *(const float4*)&BG[j*16 + tx][n];
        #pragma unroll
        for (int i = 0; i < 4; i++)
            #pragma unroll
            for (int j = 0; j < 4; j++)
                g[i][j] += a[i].x*bb[j].x + a[i].y*bb[j].y + a[i].z*bb[j].z + a[i].w*bb[j].w;
    }
    __syncthreads();            // all m1 reads of B done
    // G'[l][s] = tril * exp(acs_l - acs_s) * dt_s   (dt folded in, X stays raw)
    #pragma unroll
    for (int i = 0; i < 4; i++) {
        int l = i*16 + ty;
        #pragma unroll
        for (int j = 0; j < 4; j++) {
            int s = j*16 + tx;
            BG[l][s] = (s <= l) ? g[i][j] * expf(acs[l] - acs[s]) * dts[s] : 0.f;
        }
    }
    __syncthreads();
    // m2 (outer over s): yd[i][j] = sum_s G'[16i+ty][s] * Xr[s][16j+tx]
    float yd[4][4] = {};
    for (int s = 0; s < 64; s++) {
        float a0 = BG[ty][s], a1 = BG[16+ty][s], a2 = BG[32+ty][s], a3 = BG[48+ty][s];
        float x0 = Xr[s][tx], x1 = Xr[s][16+tx], x2 = Xr[s][32+tx], x3 = Xr[s][48+tx];
        yd[0][0]+=a0*x0; yd[0][1]+=a0*x1; yd[0][2]+=a0*x2; yd[0][3]+=a0*x3;
        yd[1][0]+=a1*x0; yd[1][1]+=a1*x1; yd[1][2]+=a1*x2; yd[1][3]+=a1*x3;
        yd[2][0]+=a2*x0; yd[2][1]+=a2*x1; yd[2][2]+=a2*x2; yd[2][3]+=a2*x3;
        yd[3][0]+=a3*x0; yd[3][1]+=a3*x1; yd[3][2]+=a3*x2; yd[3][3]+=a3*x3;
    }
    __syncthreads();            // all m2 reads of Xr done
    {   // write S_in into Xr ([p][n], same pattern as staging)
        int p = t >> 2, c0 = (t & 3) * 16;
        #pragma unroll
        for (int i = 0; i < 4; i++) *(float4*)&Xr[p][c0 + i*4] = sreg[i];
    }
    __syncthreads();
    // m3 (dot): yo[i][j] = sum_n Cs[16i+ty][n] * S[16j+tx][n]
    float yo[4][4] = {};
    for (int n = 0; n < 64; n += 4) {
        float4 a[4], ss[4];
        #pragma unroll
        for (int i = 0; i < 4; i++) a[i]  = *(const float4*)&Cs[i*16 + ty][n];
        #pragma unroll
        for (int j = 0; j < 4; j++) ss[j] = *(const float4*)&Xr[j*16 + tx][n];
        #pragma unroll
        for (int i = 0; i < 4; i++)
            #pragma unroll
            for (int j = 0; j < 4; j++)
                yo[i][j] += a[i].x*ss[j].x + a[i].y*ss[j].y + a[i].z*ss[j].z + a[i].w*ss[j].w;
    }
    float Dh = Dv[hh];
    #pragma unroll
    for (int i = 0; i < 4; i++) {
        int l = i*16 + ty;
        int row = b * SEQ + c * 64 + l;
        float el = expf(acs[l]);
        #pragma unroll
        for (int j = 0; j < 4; j++) {
            int p = j*16 + tx;
            Y[(size_t)row * DINNER + hh * 64 + p] = yd[i][j] + el * yo[i][j] + Dh * xkeep[i][j];
        }
    }
}

// --------------------------------------------------- gated RMSNorm -> bf16
__global__ __launch_bounds__(256) void rms_kernel(
    const float* __restrict__ Y, const float* __restrict__ zx,
    const float* __restrict__ nw, bf16* __restrict__ yn) {
    int row = blockIdx.x;
    const float* yr = Y + (size_t)row * DINNER;
    const float* zr = zx + (size_t)row * NPAD;      // z = cols [0, 2048)
    bf16* outr = yn + (size_t)row * DINNER;
    int t = threadIdx.x;
    float vals[8];
    float ss = 0.f;
    #pragma unroll
    for (int i = 0; i < 8; i++) {
        int idx = t + i * 256;
        float z = zr[idx];
        float v = yr[idx] * (z / (1.f + expf(-z)));
        vals[i] = v;
        ss += v * v;
    }
    for (int o = 32; o > 0; o >>= 1) ss += __shfl_down(ss, o);
    __shared__ float red[4];
    int wid = t >> 6, lane = t & 63;
    if (lane == 0) red[wid] = ss;
    __syncthreads();
    if (t == 0) { float a = 0; for (int i = 0; i < 4; i++) a += red[i]; red[0] = a; }
    __syncthreads();
    float r = rsqrtf(red[0] * (1.f / DINNER) + EPSF);
    #pragma unroll
    for (int i = 0; i < 8; i++) {
        int idx = t + i * 256;
        outr[idx] = (bf16)(vals[i] * r * nw[idx]);
    }
}

// ---------------------------------------------------------------------------
extern "C" void kernel_launch(void* const* d_in, const int* in_sizes, int n_in,
                              void* d_out, int out_size, void* d_ws, size_t ws_size,
                              hipStream_t stream) {
    const float* x          = (const float*)d_in[0];
    const float* ln_w       = (const float*)d_in[1];
    const float* ln_b       = (const float*)d_in[2];
    const float* in_proj_w  = (const float*)d_in[3];
    const float* conv_w     = (const float*)d_in[4];
    const float* conv_b     = (const float*)d_in[5];
    const float* dt_bias    = (const float*)d_in[6];
    const float* A_log      = (const float*)d_in[7];
    const float* Dv         = (const float*)d_in[8];
    const float* norm_w     = (const float*)d_in[9];
    const float* out_proj_w = (const float*)d_in[10];
    float* out = (float*)d_out;

    char* ws = (char*)d_ws;
    size_t off = 0;
    auto alloc = [&](size_t bytes) { char* p = ws + off; off += (bytes + 255) & ~(size_t)255; return p; };
    bf16*  h_bf  = (bf16*) alloc((size_t)4096 * DMODEL * 2);     //  8.4 MB
    float* zx    = (float*)alloc((size_t)4096 * NPAD * 4);       // 71.3 MB
    float* xs    = (float*)alloc((size_t)4096 * DINNER * 4);     // 33.6 MB
    float* states= (float*)alloc((size_t)2048 * 4096 * 4);       // 33.6 MB
    float* Yb    = (float*)alloc((size_t)4096 * DINNER * 4);     // 33.6 MB
    bf16*  Bt1   = (bf16*) alloc((size_t)NPAD * DMODEL * 2);     //  8.9 MB
    float* dtb   = (float*)alloc((size_t)4096 * NHEADS * 4);     //  0.5 MB
    float* Acs   = (float*)alloc((size_t)2 * NHEADS * NCHUNK * 64 * 4);
    float* Bm = (float*)h_bf;
    float* Cm = (float*)(h_bf + (size_t)2 * 1024 * 1024);
    bf16* Bt2 = Bt1;
    bf16* yn = (bf16*)xs;

    ln_kernel<<<BATCH * SEQ, 256, 0, stream>>>(x, ln_w, ln_b, h_bf);

    {   // in_proj_w (1024 x 4256) -> Bt1 [4352][1024]
        dim3 g(NPAD / 32, DMODEL / 32);
        cvt_w_kernel<<<g, 256, 0, stream>>>(in_proj_w, Bt1, DMODEL, DINPROJ, NPAD);
    }
    {   // zx = h @ in_proj_w
        dim3 g(NPAD / 128, (BATCH * SEQ) / 128);
        gemm_bf16_kernel<<<g, 256, 0, stream>>>(h_bf, Bt1, zx,
                                                BATCH * SEQ, NPAD, DMODEL, nullptr);
    }

    conv_kernel<<<(BATCH * SEQ * CONVDIM) / 256, 256, 0, stream>>>(
        zx, conv_w, conv_b, xs, Bm, Cm);

    dt_kernel<<<(BATCH * SEQ * NHEADS) / 256, 256, 0, stream>>>(zx, dt_bias, dtb);

    ssd_states_kernel<<<BATCH * NCHUNK * NHEADS, 256, 0, stream>>>(
        xs, Bm, dtb, A_log, states, Acs);

    ssd_scan_kernel<<<BATCH * NHEADS * 8, 256, 0, stream>>>(states, Acs);

    ssd_out_kernel<<<BATCH * NCHUNK * NHEADS, 256, 0, stream>>>(
        xs, Bm, Cm, dtb, states, Acs, Dv, Yb);

    rms_kernel<<<BATCH * SEQ, 256, 0, stream>>>(Yb, zx, norm_w, yn);

    {   // out_proj_w (2048 x 1024) -> Bt2 [1024][2048]
        dim3 g(DMODEL / 32, DINNER / 32);
        cvt_w_kernel<<<g, 256, 0, stream>>>(out_proj_w, Bt2, DINNER, DMODEL, DMODEL);
    }
    {   // out = yn @ out_proj_w + x
        dim3 g(DMODEL / 128, (BATCH * SEQ) / 128);
        gemm_bf16_kernel<<<g, 256, 0, stream>>>(yn, Bt2, out,
                                                BATCH * SEQ, DMODEL, DINNER, x);
    }
}

// Round 4
// 270.183 us; speedup vs baseline: 3.7758x; 1.1131x over previous
//
#include <hip/hip_runtime.h>
#include <hip/hip_bf16.h>

#define BATCH   2
#define SEQ     2048
#define DMODEL  1024
#define DINNER  2048
#define DSTATE  64
#define NHEADS  32
#define HEADDIM 64
#define CONVDIM 2176
#define DINPROJ 4256
#define NPAD    4352        // DINPROJ padded to 34*128 for the MFMA GEMM
#define NCHUNK  32          // SEQ / 64
#define EPSF    1e-5f

typedef __bf16 bf16;
typedef bf16  bf16x8 __attribute__((ext_vector_type(8)));
typedef float f32x4  __attribute__((ext_vector_type(4)));

__device__ __forceinline__ void gll16(const bf16* g, bf16* l) {
    __builtin_amdgcn_global_load_lds(
        (const __attribute__((address_space(1))) void*)g,
        (__attribute__((address_space(3))) void*)l, 16, 0, 0);
}

// ---------------------------------------------------------------- LayerNorm -> bf16
__global__ __launch_bounds__(256) void ln_kernel(
    const float* __restrict__ x, const float* __restrict__ w,
    const float* __restrict__ bv, bf16* __restrict__ h) {
    int row = blockIdx.x;                    // 4096 rows
    const float* xr = x + (size_t)row * DMODEL;
    bf16* hr = h + (size_t)row * DMODEL;
    int t = threadIdx.x;
    float4 v = ((const float4*)xr)[t];
    float s  = v.x + v.y + v.z + v.w;
    float ss = v.x*v.x + v.y*v.y + v.z*v.z + v.w*v.w;
    for (int o = 32; o > 0; o >>= 1) { s += __shfl_down(s, o); ss += __shfl_down(ss, o); }
    __shared__ float red[2][4];
    int wid = t >> 6, lane = t & 63;
    if (lane == 0) { red[0][wid] = s; red[1][wid] = ss; }
    __syncthreads();
    if (t == 0) {
        float a = 0, b2 = 0;
        for (int i = 0; i < 4; i++) { a += red[0][i]; b2 += red[1][i]; }
        red[0][0] = a; red[1][0] = b2;
    }
    __syncthreads();
    float mean = red[0][0] * (1.f / DMODEL);
    float var  = red[1][0] * (1.f / DMODEL) - mean * mean;
    float rstd = rsqrtf(var + EPSF);
    for (int i = t; i < DMODEL; i += 256)
        hr[i] = (bf16)((xr[i] - mean) * rstd * w[i] + bv[i]);
}

// -------------------------------------------- weight transpose + bf16 cast (+pad)
__global__ __launch_bounds__(256) void cvt_w_kernel(
    const float* __restrict__ W, bf16* __restrict__ Bt, int K, int N, int NP) {
    __shared__ float sm[32][33];
    int n0 = blockIdx.x * 32, k0 = blockIdx.y * 32;
    int tx = threadIdx.x & 31, ty = threadIdx.x >> 5;   // 32 x 8
    for (int i = 0; i < 4; i++) {
        int k = k0 + ty + i * 8, n = n0 + tx;
        sm[ty + i * 8][tx] = (n < N) ? W[(size_t)k * N + n] : 0.f;
    }
    __syncthreads();
    for (int i = 0; i < 4; i++) {
        int n = n0 + ty + i * 8, k = k0 + tx;
        if (n < NP) Bt[(size_t)n * K + k] = (bf16)sm[tx][ty + i * 8];
    }
}

// ------------------------------------------- bf16 MFMA GEMM, 2-phase pipelined
// C[M][N] = A[M][K] @ Bt[N][K]^T (+resid). Tile BM x BN, BK=32, dbuf LDS.
// 4 waves: wave (wm,wn) owns (BM/2)x(BN/2). Stage t+1 issued BEFORE compute of t;
// the single __syncthreads() per step drains the prefetch after compute hid it.
template<int BM, int BN, typename OUT_T>
__global__ __launch_bounds__(256) void gemm_bf16_pipe(
    const bf16* __restrict__ A, const bf16* __restrict__ Bt,
    OUT_T* __restrict__ C, int M, int N, int K,
    const float* __restrict__ resid) {
    constexpr int MR = BM / 32;              // fragments per wave in M (BM/2/16)
    constexpr int NR = BN / 32;
    __shared__ __align__(16) bf16 sA[2][BM * 32];
    __shared__ __align__(16) bf16 sB[2][BN * 32];
    int t = threadIdx.x;
    int lane = t & 63, w = t >> 6;
    int m0 = blockIdx.y * BM, n0 = blockIdx.x * BN;
    int wm = w >> 1, wn = w & 1;
    f32x4 acc[MR][NR] = {};
    int srow = w * 16 + (lane >> 2);         // staging row within 64-row group
    int scol = (lane & 3) * 8;
    int fr = lane & 15;
    int fc = (lane >> 4) * 8;
    auto stage = [&](int buf, int k0) {
        #pragma unroll
        for (int i = 0; i < BM / 64; i++)
            gll16(&A[(size_t)(m0 + i * 64 + srow) * K + k0 + scol],
                  &sA[buf][(i * 64 + w * 16) * 32]);
        #pragma unroll
        for (int i = 0; i < BN / 64; i++)
            gll16(&Bt[(size_t)(n0 + i * 64 + srow) * K + k0 + scol],
                  &sB[buf][(i * 64 + w * 16) * 32]);
    };
    int nt = K / 32;
    stage(0, 0);
    __syncthreads();                         // implicit vmcnt(0): buf0 ready
    int cur = 0;
    for (int tt = 0; tt < nt; tt++) {
        if (tt + 1 < nt) stage(cur ^ 1, (tt + 1) * 32);   // prefetch in flight
        bf16x8 af[MR], bfr[NR];
        #pragma unroll
        for (int i = 0; i < MR; i++)
            af[i] = *(const bf16x8*)&sA[cur][(wm * (BM/2) + i * 16 + fr) * 32 + fc];
        #pragma unroll
        for (int j = 0; j < NR; j++)
            bfr[j] = *(const bf16x8*)&sB[cur][(wn * (BN/2) + j * 16 + fr) * 32 + fc];
        #pragma unroll
        for (int i = 0; i < MR; i++)
            #pragma unroll
            for (int j = 0; j < NR; j++)
                acc[i][j] = __builtin_amdgcn_mfma_f32_16x16x32_bf16(
                    af[i], bfr[j], acc[i][j], 0, 0, 0);
        __syncthreads();                     // drains prefetch; buf[cur^1] ready
        cur ^= 1;
    }
    #pragma unroll
    for (int i = 0; i < MR; i++) {
        #pragma unroll
        for (int j = 0; j < NR; j++) {
            int col = n0 + wn * (BN/2) + j * 16 + (lane & 15);
            #pragma unroll
            for (int r = 0; r < 4; r++) {
                int row = m0 + wm * (BM/2) + i * 16 + (lane >> 4) * 4 + r;
                float v = acc[i][j][r];
                if (resid) v += resid[(size_t)row * N + col];
                C[(size_t)row * N + col] = (OUT_T)v;
            }
        }
    }
}

// ------------------------------------------------- causal depthwise conv + SiLU
__global__ __launch_bounds__(256) void conv_kernel(
    const bf16* __restrict__ zx, const float* __restrict__ cw,
    const float* __restrict__ cb, float* __restrict__ xs,
    float* __restrict__ Bm, float* __restrict__ Cm) {
    int idx = blockIdx.x * 256 + threadIdx.x;        // b*l*CONVDIM
    int ch = idx % CONVDIM;
    int bl = idx / CONVDIM;
    int b = bl / SEQ, tt = bl % SEQ;
    float acc = cb[ch];
    #pragma unroll
    for (int k = 0; k < 4; k++) {
        int tp = tt - 3 + k;
        if (tp >= 0)
            acc += (float)zx[(size_t)(b * SEQ + tp) * NPAD + DINNER + ch] * cw[ch * 4 + k];
    }
    float s = acc / (1.f + expf(-acc));
    if (ch < DINNER)              xs[(size_t)bl * DINNER + ch] = s;
    else if (ch < DINNER+DSTATE)  Bm[bl * DSTATE + (ch - DINNER)] = s;
    else                          Cm[bl * DSTATE + (ch - DINNER - DSTATE)] = s;
}

// ---------------------------------------------------------------- dt softplus
__global__ __launch_bounds__(256) void dt_kernel(
    const bf16* __restrict__ zx, const float* __restrict__ dt_bias,
    float* __restrict__ dtb) {
    int idx = blockIdx.x * 256 + threadIdx.x;        // b*l*NHEADS
    int hh = idx % NHEADS;
    int bl = idx / NHEADS;
    float v = (float)zx[(size_t)bl * NPAD + (DINNER + CONVDIM) + hh] + dt_bias[hh];
    dtb[idx] = (v > 20.f) ? v : log1pf(expf(v));
}

// ----------------------------------------- SSD: per-chunk local states + A_cs
__global__ __launch_bounds__(256) void ssd_states_kernel(
    const float* __restrict__ xs, const float* __restrict__ Bm,
    const float* __restrict__ dtb, const float* __restrict__ A_log,
    float* __restrict__ states, float* __restrict__ Acs_g) {
    int blk = blockIdx.x;
    int hh = blk % NHEADS;
    int bc = blk / NHEADS;
    int c = bc % NCHUNK, b = bc / NCHUNK;
    __shared__ float Xd[64][64];
    __shared__ float Bw[64][64];
    __shared__ float dts[64];
    __shared__ float acs[64];
    int t = threadIdx.x;
    float Ah = -expf(A_log[hh]);
    if (t < 64) {                                // wave 0: load + parallel scan
        float dv = dtb[(b * SEQ + c * 64 + t) * NHEADS + hh];
        dts[t] = dv;
        float v = dv * Ah;
        #pragma unroll
        for (int o = 1; o < 64; o <<= 1) {
            float p = __shfl_up(v, o);
            if (t >= o) v += p;
        }
        acs[t] = v;
    }
    __syncthreads();
    float alast = acs[63];
    if (t < 64)
        Acs_g[((b * NHEADS + hh) * NCHUNK + c) * 64 + t] = acs[t];
    for (int i = 0; i < 16; i++) {
        int e = t + i * 256;
        int l = e >> 6, col = e & 63;
        int row = b * SEQ + c * 64 + l;
        Xd[l][col] = xs[(size_t)row * DINNER + hh * 64 + col] * dts[l];
        Bw[l][col] = Bm[row * DSTATE + col] * expf(alast - acs[l]);
    }
    __syncthreads();
    int tx = t & 15, ty = t >> 4;
    float acc[4][4] = {};
    for (int l = 0; l < 64; l++) {
        float a0 = Xd[l][ty*4+0], a1 = Xd[l][ty*4+1],
              a2 = Xd[l][ty*4+2], a3 = Xd[l][ty*4+3];
        float b0 = Bw[l][tx*4+0], b1 = Bw[l][tx*4+1],
              b2 = Bw[l][tx*4+2], b3 = Bw[l][tx*4+3];
        acc[0][0]+=a0*b0; acc[0][1]+=a0*b1; acc[0][2]+=a0*b2; acc[0][3]+=a0*b3;
        acc[1][0]+=a1*b0; acc[1][1]+=a1*b1; acc[1][2]+=a1*b2; acc[1][3]+=a1*b3;
        acc[2][0]+=a2*b0; acc[2][1]+=a2*b1; acc[2][2]+=a2*b2; acc[2][3]+=a2*b3;
        acc[3][0]+=a3*b0; acc[3][1]+=a3*b1; acc[3][2]+=a3*b2; acc[3][3]+=a3*b3;
    }
    float* outp = states + (size_t)blk * 4096;
    for (int i = 0; i < 4; i++)
        for (int j = 0; j < 4; j++)
            outp[(ty*4+i) * 64 + tx*4 + j] = acc[i][j];
}

// ------------------------------------------- SSD: inter-chunk sequential scan
__global__ __launch_bounds__(256) void ssd_scan_kernel(
    float* __restrict__ states, const float* __restrict__ Acs_g) {
    int bid = blockIdx.x;
    int slice = bid & 7, bh = bid >> 3;
    int hh = bh % NHEADS, b = bh / NHEADS;
    int e0 = slice * 512 + threadIdx.x * 2;
    float2 loc[NCHUNK];
    float dec[NCHUNK];
    #pragma unroll
    for (int c = 0; c < NCHUNK; c++) {
        loc[c] = *(const float2*)&states[(size_t)((b*NCHUNK+c)*NHEADS+hh)*4096 + e0];
        dec[c] = expf(Acs_g[((b*NHEADS+hh)*NCHUNK + c)*64 + 63]);
    }
    float2 S = make_float2(0.f, 0.f);
    #pragma unroll
    for (int c = 0; c < NCHUNK; c++) {
        float2 l = loc[c];
        *(float2*)&states[(size_t)((b*NCHUNK+c)*NHEADS+hh)*4096 + e0] = S;
        S.x = dec[c]*S.x + l.x;
        S.y = dec[c]*S.y + l.y;
    }
}

// --------------------------------- SSD: Y = Y_diag + Y_off + D*X   per chunk
__global__ __launch_bounds__(256) void ssd_out_kernel(
    const float* __restrict__ xs, const float* __restrict__ Bm,
    const float* __restrict__ Cm, const float* __restrict__ dtb,
    const float* __restrict__ states, const float* __restrict__ Acs_g,
    const float* __restrict__ Dv, float* __restrict__ Y) {
    int blk = blockIdx.x;
    int hh = blk % NHEADS;
    int bc = blk / NHEADS;
    int c = bc % NCHUNK, b = bc / NCHUNK;
    __shared__ float Cs[64][68];
    __shared__ float BG[64][68];     // B, then G' = tril(CB^T * decay) * dt
    __shared__ float Xr[64][68];     // raw X, then S_in
    __shared__ float acs[64], dts[64];
    int t = threadIdx.x;
    float4 sreg[4];
    {
        const float* sp = states + (size_t)blk * 4096 + t * 16;
        #pragma unroll
        for (int i = 0; i < 4; i++) sreg[i] = *(const float4*)&sp[i * 4];
    }
    if (t < 64) {
        acs[t] = Acs_g[((b * NHEADS + hh) * NCHUNK + c) * 64 + t];
        dts[t] = dtb[(b * SEQ + c * 64 + t) * NHEADS + hh];
    }
    {
        int l = t >> 2, c0 = (t & 3) * 16;
        int row = b * SEQ + c * 64 + l;
        #pragma unroll
        for (int i = 0; i < 4; i++) {
            *(float4*)&Cs[l][c0 + i*4] = *(const float4*)&Cm[row * DSTATE + c0 + i*4];
            *(float4*)&BG[l][c0 + i*4] = *(const float4*)&Bm[row * DSTATE + c0 + i*4];
            *(float4*)&Xr[l][c0 + i*4] = *(const float4*)&xs[(size_t)row * DINNER + hh * 64 + c0 + i*4];
        }
    }
    __syncthreads();
    int tx = t & 15, ty = t >> 4;
    float xkeep[4][4];
    #pragma unroll
    for (int i = 0; i < 4; i++)
        #pragma unroll
        for (int j = 0; j < 4; j++)
            xkeep[i][j] = Xr[i*16 + ty][j*16 + tx];
    float g[4][4] = {};
    for (int n = 0; n < 64; n += 4) {
        float4 a[4], bb[4];
        #pragma unroll
        for (int i = 0; i < 4; i++) a[i]  = *(const float4*)&Cs[i*16 + ty][n];
        #pragma unroll
        for (int j = 0; j < 4; j++) bb[j] = *(const float4*)&BG[j*16 + tx][n];
        #pragma unroll
        for (int i = 0; i < 4; i++)
            #pragma unroll
            for (int j = 0; j < 4; j++)
                g[i][j] += a[i].x*bb[j].x + a[i].y*bb[j].y + a[i].z*bb[j].z + a[i].w*bb[j].w;
    }
    __syncthreads();
    #pragma unroll
    for (int i = 0; i < 4; i++) {
        int l = i*16 + ty;
        #pragma unroll
        for (int j = 0; j < 4; j++) {
            int s = j*16 + tx;
            BG[l][s] = (s <= l) ? g[i][j] * expf(acs[l] - acs[s]) * dts[s] : 0.f;
        }
    }
    __syncthreads();
    float yd[4][4] = {};
    for (int s = 0; s < 64; s++) {
        float a0 = BG[ty][s], a1 = BG[16+ty][s], a2 = BG[32+ty][s], a3 = BG[48+ty][s];
        float x0 = Xr[s][tx], x1 = Xr[s][16+tx], x2 = Xr[s][32+tx], x3 = Xr[s][48+tx];
        yd[0][0]+=a0*x0; yd[0][1]+=a0*x1; yd[0][2]+=a0*x2; yd[0][3]+=a0*x3;
        yd[1][0]+=a1*x0; yd[1][1]+=a1*x1; yd[1][2]+=a1*x2; yd[1][3]+=a1*x3;
        yd[2][0]+=a2*x0; yd[2][1]+=a2*x1; yd[2][2]+=a2*x2; yd[2][3]+=a2*x3;
        yd[3][0]+=a3*x0; yd[3][1]+=a3*x1; yd[3][2]+=a3*x2; yd[3][3]+=a3*x3;
    }
    __syncthreads();
    {
        int p = t >> 2, c0 = (t & 3) * 16;
        #pragma unroll
        for (int i = 0; i < 4; i++) *(float4*)&Xr[p][c0 + i*4] = sreg[i];
    }
    __syncthreads();
    float yo[4][4] = {};
    for (int n = 0; n < 64; n += 4) {
        float4 a[4], ss[4];
        #pragma unroll
        for (int i = 0; i < 4; i++) a[i]  = *(const float4*)&Cs[i*16 + ty][n];
        #pragma unroll
        for (int j = 0; j < 4; j++) ss[j] = *(const float4*)&Xr[j*16 + tx][n];
        #pragma unroll
        for (int i = 0; i < 4; i++)
            #pragma unroll
            for (int j = 0; j < 4; j++)
                yo[i][j] += a[i].x*ss[j].x + a[i].y*ss[j].y + a[i].z*ss[j].z + a[i].w*ss[j].w;
    }
    float Dh = Dv[hh];
    #pragma unroll
    for (int i = 0; i < 4; i++) {
        int l = i*16 + ty;
        int row = b * SEQ + c * 64 + l;
        float el = expf(acs[l]);
        #pragma unroll
        for (int j = 0; j < 4; j++) {
            int p = j*16 + tx;
            Y[(size_t)row * DINNER + hh * 64 + p] = yd[i][j] + el * yo[i][j] + Dh * xkeep[i][j];
        }
    }
}

// --------------------------------------------------- gated RMSNorm -> bf16
__global__ __launch_bounds__(256) void rms_kernel(
    const float* __restrict__ Y, const bf16* __restrict__ zx,
    const float* __restrict__ nw, bf16* __restrict__ yn) {
    int row = blockIdx.x;
    const float* yr = Y + (size_t)row * DINNER;
    const bf16* zr = zx + (size_t)row * NPAD;       // z = cols [0, 2048)
    bf16* outr = yn + (size_t)row * DINNER;
    int t = threadIdx.x;
    float vals[8];
    float ss = 0.f;
    #pragma unroll
    for (int i = 0; i < 8; i++) {
        int idx = t + i * 256;
        float z = (float)zr[idx];
        float v = yr[idx] * (z / (1.f + expf(-z)));
        vals[i] = v;
        ss += v * v;
    }
    for (int o = 32; o > 0; o >>= 1) ss += __shfl_down(ss, o);
    __shared__ float red[4];
    int wid = t >> 6, lane = t & 63;
    if (lane == 0) red[wid] = ss;
    __syncthreads();
    if (t == 0) { float a = 0; for (int i = 0; i < 4; i++) a += red[i]; red[0] = a; }
    __syncthreads();
    float r = rsqrtf(red[0] * (1.f / DINNER) + EPSF);
    #pragma unroll
    for (int i = 0; i < 8; i++) {
        int idx = t + i * 256;
        outr[idx] = (bf16)(vals[i] * r * nw[idx]);
    }
}

// ---------------------------------------------------------------------------
extern "C" void kernel_launch(void* const* d_in, const int* in_sizes, int n_in,
                              void* d_out, int out_size, void* d_ws, size_t ws_size,
                              hipStream_t stream) {
    const float* x          = (const float*)d_in[0];
    const float* ln_w       = (const float*)d_in[1];
    const float* ln_b       = (const float*)d_in[2];
    const float* in_proj_w  = (const float*)d_in[3];
    const float* conv_w     = (const float*)d_in[4];
    const float* conv_b     = (const float*)d_in[5];
    const float* dt_bias    = (const float*)d_in[6];
    const float* A_log      = (const float*)d_in[7];
    const float* Dv         = (const float*)d_in[8];
    const float* norm_w     = (const float*)d_in[9];
    const float* out_proj_w = (const float*)d_in[10];
    float* out = (float*)d_out;

    char* ws = (char*)d_ws;
    size_t off = 0;
    auto alloc = [&](size_t bytes) { char* p = ws + off; off += (bytes + 255) & ~(size_t)255; return p; };
    bf16*  h_bf  = (bf16*) alloc((size_t)4096 * DMODEL * 2);     //  8.4 MB
    bf16*  zx    = (bf16*) alloc((size_t)4096 * NPAD * 2);       // 35.6 MB
    float* xs    = (float*)alloc((size_t)4096 * DINNER * 4);     // 33.6 MB
    float* states= (float*)alloc((size_t)2048 * 4096 * 4);       // 33.6 MB
    float* Yb    = (float*)alloc((size_t)4096 * DINNER * 4);     // 33.6 MB
    bf16*  Bt1   = (bf16*) alloc((size_t)NPAD * DMODEL * 2);     //  8.9 MB
    float* dtb   = (float*)alloc((size_t)4096 * NHEADS * 4);     //  0.5 MB
    float* Acs   = (float*)alloc((size_t)2 * NHEADS * NCHUNK * 64 * 4);
    float* Bm = (float*)h_bf;
    float* Cm = (float*)(h_bf + (size_t)2 * 1024 * 1024);
    bf16* Bt2 = Bt1;
    bf16* yn = (bf16*)xs;

    ln_kernel<<<BATCH * SEQ, 256, 0, stream>>>(x, ln_w, ln_b, h_bf);

    {   // in_proj_w (1024 x 4256) -> Bt1 [4352][1024]
        dim3 g(NPAD / 32, DMODEL / 32);
        cvt_w_kernel<<<g, 256, 0, stream>>>(in_proj_w, Bt1, DMODEL, DINPROJ, NPAD);
    }
    {   // zx = h @ in_proj_w   (bf16 out)
        dim3 g(NPAD / 128, (BATCH * SEQ) / 128);
        gemm_bf16_pipe<128, 128, bf16><<<g, 256, 0, stream>>>(
            h_bf, Bt1, zx, BATCH * SEQ, NPAD, DMODEL, nullptr);
    }

    conv_kernel<<<(BATCH * SEQ * CONVDIM) / 256, 256, 0, stream>>>(
        zx, conv_w, conv_b, xs, Bm, Cm);

    dt_kernel<<<(BATCH * SEQ * NHEADS) / 256, 256, 0, stream>>>(zx, dt_bias, dtb);

    ssd_states_kernel<<<BATCH * NCHUNK * NHEADS, 256, 0, stream>>>(
        xs, Bm, dtb, A_log, states, Acs);

    ssd_scan_kernel<<<BATCH * NHEADS * 8, 256, 0, stream>>>(states, Acs);

    ssd_out_kernel<<<BATCH * NCHUNK * NHEADS, 256, 0, stream>>>(
        xs, Bm, Cm, dtb, states, Acs, Dv, Yb);

    rms_kernel<<<BATCH * SEQ, 256, 0, stream>>>(Yb, zx, norm_w, yn);

    {   // out_proj_w (2048 x 1024) -> Bt2 [1024][2048]
        dim3 g(DMODEL / 32, DINNER / 32);
        cvt_w_kernel<<<g, 256, 0, stream>>>(out_proj_w, Bt2, DINNER, DMODEL, DMODEL);
    }
    {   // out = yn @ out_proj_w + x   (128x64 tiles -> 512 blocks)
        dim3 g(DMODEL / 64, (BATCH * SEQ) / 128);
        gemm_bf16_pipe<128, 64, float><<<g, 256, 0, stream>>>(
            yn, Bt2, out, BATCH * SEQ, DMODEL, DINNER, x);
    }
}

// Round 5
// 219.608 us; speedup vs baseline: 4.6453x; 1.2303x over previous
//
#include <hip/hip_runtime.h>
#include <hip/hip_bf16.h>

#define BATCH   2
#define SEQ     2048
#define DMODEL  1024
#define DINNER  2048
#define DSTATE  64
#define NHEADS  32
#define HEADDIM 64
#define CONVDIM 2176
#define DINPROJ 4256
#define NPAD    4352        // DINPROJ padded to 34*128 for the MFMA GEMM
#define NCHUNK  32          // SEQ / 64
#define EPSF    1e-5f
#define SP      88          // LDS row stride (bf16): 176B = 16B-aligned, 44dw%32=12 -> ~2-way

typedef __bf16 bf16;
typedef bf16  bf16x8 __attribute__((ext_vector_type(8)));
typedef float f32x4  __attribute__((ext_vector_type(4)));

__device__ __forceinline__ void gll16(const bf16* g, bf16* l) {
    __builtin_amdgcn_global_load_lds(
        (const __attribute__((address_space(1))) void*)g,
        (__attribute__((address_space(3))) void*)l, 16, 0, 0);
}

// ---------------------------------------------------------------- LayerNorm -> bf16
__global__ __launch_bounds__(256) void ln_kernel(
    const float* __restrict__ x, const float* __restrict__ w,
    const float* __restrict__ bv, bf16* __restrict__ h) {
    int row = blockIdx.x;                    // 4096 rows
    const float* xr = x + (size_t)row * DMODEL;
    bf16* hr = h + (size_t)row * DMODEL;
    int t = threadIdx.x;
    float4 v = ((const float4*)xr)[t];
    float s  = v.x + v.y + v.z + v.w;
    float ss = v.x*v.x + v.y*v.y + v.z*v.z + v.w*v.w;
    for (int o = 32; o > 0; o >>= 1) { s += __shfl_down(s, o); ss += __shfl_down(ss, o); }
    __shared__ float red[2][4];
    int wid = t >> 6, lane = t & 63;
    if (lane == 0) { red[0][wid] = s; red[1][wid] = ss; }
    __syncthreads();
    if (t == 0) {
        float a = 0, b2 = 0;
        for (int i = 0; i < 4; i++) { a += red[0][i]; b2 += red[1][i]; }
        red[0][0] = a; red[1][0] = b2;
    }
    __syncthreads();
    float mean = red[0][0] * (1.f / DMODEL);
    float var  = red[1][0] * (1.f / DMODEL) - mean * mean;
    float rstd = rsqrtf(var + EPSF);
    for (int i = t; i < DMODEL; i += 256)
        hr[i] = (bf16)((xr[i] - mean) * rstd * w[i] + bv[i]);
}

// -------------------------------------------- weight transpose + bf16 cast (+pad)
__global__ __launch_bounds__(256) void cvt_w_kernel(
    const float* __restrict__ W, bf16* __restrict__ Bt, int K, int N, int NP) {
    __shared__ float sm[32][33];
    int n0 = blockIdx.x * 32, k0 = blockIdx.y * 32;
    int tx = threadIdx.x & 31, ty = threadIdx.x >> 5;   // 32 x 8
    for (int i = 0; i < 4; i++) {
        int k = k0 + ty + i * 8, n = n0 + tx;
        sm[ty + i * 8][tx] = (n < N) ? W[(size_t)k * N + n] : 0.f;
    }
    __syncthreads();
    for (int i = 0; i < 4; i++) {
        int n = n0 + ty + i * 8, k = k0 + tx;
        if (n < NP) Bt[(size_t)n * K + k] = (bf16)sm[tx][ty + i * 8];
    }
}

// ------------------------------------------- bf16 MFMA GEMM, 2-phase pipelined
template<int BM, int BN, typename OUT_T>
__global__ __launch_bounds__(256) void gemm_bf16_pipe(
    const bf16* __restrict__ A, const bf16* __restrict__ Bt,
    OUT_T* __restrict__ C, int M, int N, int K,
    const float* __restrict__ resid) {
    constexpr int MR = BM / 32;
    constexpr int NR = BN / 32;
    __shared__ __align__(16) bf16 sA[2][BM * 32];
    __shared__ __align__(16) bf16 sB[2][BN * 32];
    int t = threadIdx.x;
    int lane = t & 63, w = t >> 6;
    int m0 = blockIdx.y * BM, n0 = blockIdx.x * BN;
    int wm = w >> 1, wn = w & 1;
    f32x4 acc[MR][NR] = {};
    int srow = w * 16 + (lane >> 2);
    int scol = (lane & 3) * 8;
    int fr = lane & 15;
    int fc = (lane >> 4) * 8;
    auto stage = [&](int buf, int k0) {
        #pragma unroll
        for (int i = 0; i < BM / 64; i++)
            gll16(&A[(size_t)(m0 + i * 64 + srow) * K + k0 + scol],
                  &sA[buf][(i * 64 + w * 16) * 32]);
        #pragma unroll
        for (int i = 0; i < BN / 64; i++)
            gll16(&Bt[(size_t)(n0 + i * 64 + srow) * K + k0 + scol],
                  &sB[buf][(i * 64 + w * 16) * 32]);
    };
    int nt = K / 32;
    stage(0, 0);
    __syncthreads();
    int cur = 0;
    for (int tt = 0; tt < nt; tt++) {
        if (tt + 1 < nt) stage(cur ^ 1, (tt + 1) * 32);
        bf16x8 af[MR], bfr[NR];
        #pragma unroll
        for (int i = 0; i < MR; i++)
            af[i] = *(const bf16x8*)&sA[cur][(wm * (BM/2) + i * 16 + fr) * 32 + fc];
        #pragma unroll
        for (int j = 0; j < NR; j++)
            bfr[j] = *(const bf16x8*)&sB[cur][(wn * (BN/2) + j * 16 + fr) * 32 + fc];
        #pragma unroll
        for (int i = 0; i < MR; i++)
            #pragma unroll
            for (int j = 0; j < NR; j++)
                acc[i][j] = __builtin_amdgcn_mfma_f32_16x16x32_bf16(
                    af[i], bfr[j], acc[i][j], 0, 0, 0);
        __syncthreads();
        cur ^= 1;
    }
    #pragma unroll
    for (int i = 0; i < MR; i++) {
        #pragma unroll
        for (int j = 0; j < NR; j++) {
            int col = n0 + wn * (BN/2) + j * 16 + (lane & 15);
            #pragma unroll
            for (int r = 0; r < 4; r++) {
                int row = m0 + wm * (BM/2) + i * 16 + (lane >> 4) * 4 + r;
                float v = acc[i][j][r];
                if (resid) v += resid[(size_t)row * N + col];
                C[(size_t)row * N + col] = (OUT_T)v;
            }
        }
    }
}

// ------------------------------------------------- causal depthwise conv + SiLU
__global__ __launch_bounds__(256) void conv_kernel(
    const bf16* __restrict__ zx, const float* __restrict__ cw,
    const float* __restrict__ cb, bf16* __restrict__ xs,
    bf16* __restrict__ Bm, bf16* __restrict__ Cm) {
    int idx = blockIdx.x * 256 + threadIdx.x;        // b*l*CONVDIM
    int ch = idx % CONVDIM;
    int bl = idx / CONVDIM;
    int b = bl / SEQ, tt = bl % SEQ;
    float acc = cb[ch];
    #pragma unroll
    for (int k = 0; k < 4; k++) {
        int tp = tt - 3 + k;
        if (tp >= 0)
            acc += (float)zx[(size_t)(b * SEQ + tp) * NPAD + DINNER + ch] * cw[ch * 4 + k];
    }
    float s = acc / (1.f + expf(-acc));
    if (ch < DINNER)              xs[(size_t)bl * DINNER + ch] = (bf16)s;
    else if (ch < DINNER+DSTATE)  Bm[bl * DSTATE + (ch - DINNER)] = (bf16)s;
    else                          Cm[bl * DSTATE + (ch - DINNER - DSTATE)] = (bf16)s;
}

// ---------------------------------------------------------------- dt softplus
__global__ __launch_bounds__(256) void dt_kernel(
    const bf16* __restrict__ zx, const float* __restrict__ dt_bias,
    float* __restrict__ dtb) {
    int idx = blockIdx.x * 256 + threadIdx.x;        // b*l*NHEADS
    int hh = idx % NHEADS;
    int bl = idx / NHEADS;
    float v = (float)zx[(size_t)bl * NPAD + (DINNER + CONVDIM) + hh] + dt_bias[hh];
    dtb[idx] = (v > 20.f) ? v : log1pf(expf(v));
}

// ----------------------------------------- SSD: per-chunk local states (MFMA)
// states[p][n] = sum_l (X[l][p]*dt[l]) * (B[l][n]*exp(alast-acs[l]))
// Both operands staged TRANSPOSED ([p][l], [n][l]) so K=l is contiguous.
__global__ __launch_bounds__(256) void ssd_states_kernel(
    const bf16* __restrict__ xs, const bf16* __restrict__ Bm,
    const float* __restrict__ dtb, const float* __restrict__ A_log,
    float* __restrict__ states, float* __restrict__ Acs_g) {
    int blk = blockIdx.x;
    int hh = blk % NHEADS;
    int bc = blk / NHEADS;
    int c = bc % NCHUNK, b = bc / NCHUNK;
    __shared__ __align__(16) bf16 sXT[64 * SP];   // [p][l]
    __shared__ __align__(16) bf16 sBT[64 * SP];   // [n][l]
    __shared__ float dts[64], acs[64];
    int t = threadIdx.x;
    float Ah = -expf(A_log[hh]);
    if (t < 64) {                                // wave 0: load + parallel scan
        float dv = dtb[(b * SEQ + c * 64 + t) * NHEADS + hh];
        float v = dv * Ah;
        #pragma unroll
        for (int o = 1; o < 64; o <<= 1) {
            float p = __shfl_up(v, o);
            if (t >= o) v += p;
        }
        dts[t] = dv; acs[t] = v;
        Acs_g[((b * NHEADS + hh) * NCHUNK + c) * 64 + t] = v;
    }
    __syncthreads();
    float alast = acs[63];
    {   // stage transposed, weighted
        int l = t >> 2, c0 = (t & 3) * 16;
        int row = b * SEQ + c * 64 + l;
        float dl = dts[l];
        float wl = expf(alast - acs[l]);
        bf16x8 xv0 = *(const bf16x8*)&xs[(size_t)row * DINNER + hh * 64 + c0];
        bf16x8 xv1 = *(const bf16x8*)&xs[(size_t)row * DINNER + hh * 64 + c0 + 8];
        bf16x8 bv0 = *(const bf16x8*)&Bm[(size_t)row * DSTATE + c0];
        bf16x8 bv1 = *(const bf16x8*)&Bm[(size_t)row * DSTATE + c0 + 8];
        #pragma unroll
        for (int i = 0; i < 8; i++) {
            sXT[(c0 + i) * SP + l]     = (bf16)((float)xv0[i] * dl);
            sXT[(c0 + 8 + i) * SP + l] = (bf16)((float)xv1[i] * dl);
            sBT[(c0 + i) * SP + l]     = (bf16)((float)bv0[i] * wl);
            sBT[(c0 + 8 + i) * SP + l] = (bf16)((float)bv1[i] * wl);
        }
    }
    __syncthreads();
    int lane = t & 63, w = t >> 6;
    int wm = w >> 1, wn = w & 1;
    int fr = lane & 15, fc = (lane >> 4) * 8;
    f32x4 acc[2][2] = {};
    #pragma unroll
    for (int kk = 0; kk < 2; kk++) {
        bf16x8 a[2], bb[2];
        #pragma unroll
        for (int i = 0; i < 2; i++)
            a[i] = *(const bf16x8*)&sXT[(wm * 32 + i * 16 + fr) * SP + kk * 32 + fc];
        #pragma unroll
        for (int j = 0; j < 2; j++)
            bb[j] = *(const bf16x8*)&sBT[(wn * 32 + j * 16 + fr) * SP + kk * 32 + fc];
        #pragma unroll
        for (int i = 0; i < 2; i++)
            #pragma unroll
            for (int j = 0; j < 2; j++)
                acc[i][j] = __builtin_amdgcn_mfma_f32_16x16x32_bf16(
                    a[i], bb[j], acc[i][j], 0, 0, 0);
    }
    float* outp = states + (size_t)blk * 4096;
    #pragma unroll
    for (int i = 0; i < 2; i++)
        #pragma unroll
        for (int j = 0; j < 2; j++)
            #pragma unroll
            for (int r = 0; r < 4; r++)
                outp[(wm*32 + i*16 + (lane>>4)*4 + r) * 64 + wn*32 + j*16 + (lane&15)]
                    = acc[i][j][r];
}

// ------------------------------------------- SSD: inter-chunk sequential scan
__global__ __launch_bounds__(256) void ssd_scan_kernel(
    float* __restrict__ states, const float* __restrict__ Acs_g) {
    int bid = blockIdx.x;
    int slice = bid & 7, bh = bid >> 3;
    int hh = bh % NHEADS, b = bh / NHEADS;
    int e0 = slice * 512 + threadIdx.x * 2;
    float2 loc[NCHUNK];
    float dec[NCHUNK];
    #pragma unroll
    for (int c = 0; c < NCHUNK; c++) {
        loc[c] = *(const float2*)&states[(size_t)((b*NCHUNK+c)*NHEADS+hh)*4096 + e0];
        dec[c] = expf(Acs_g[((b*NHEADS+hh)*NCHUNK + c)*64 + 63]);
    }
    float2 S = make_float2(0.f, 0.f);
    #pragma unroll
    for (int c = 0; c < NCHUNK; c++) {
        float2 l = loc[c];
        *(float2*)&states[(size_t)((b*NCHUNK+c)*NHEADS+hh)*4096 + e0] = S;
        S.x = dec[c]*S.x + l.x;
        S.y = dec[c]*S.y + l.y;
    }
}

// --------------------------------- SSD: Y = Y_diag + Y_off + D*X (MFMA)
// m1: G0 = C·B^T (both row-major over n=K). G' = tril(G0*exp)*dt -> sBG.
// m2: Y_diag = G'·X (B-op = X^T tile). m3: Y_off = C·S^T (S row-major [p][n]).
__global__ __launch_bounds__(256) void ssd_out_kernel(
    const bf16* __restrict__ xs, const bf16* __restrict__ Bm,
    const bf16* __restrict__ Cm, const float* __restrict__ dtb,
    const float* __restrict__ states, const float* __restrict__ Acs_g,
    const float* __restrict__ Dv, float* __restrict__ Y) {
    int blk = blockIdx.x;
    int hh = blk % NHEADS;
    int bc = blk / NHEADS;
    int c = bc % NCHUNK, b = bc / NCHUNK;
    __shared__ __align__(16) bf16 sC [64 * SP];   // [l][n]
    __shared__ __align__(16) bf16 sBG[64 * SP];   // B[s][n] -> G'[l][s]
    __shared__ __align__(16) bf16 sXS[64 * SP];   // X^T[p][l] -> S[p][n]
    __shared__ float acs[64], dts[64];
    int t = threadIdx.x;
    float4 sreg[4];                               // T14: S prefetch to regs
    {
        const float* sp = states + (size_t)blk * 4096 + t * 16;
        #pragma unroll
        for (int i = 0; i < 4; i++) sreg[i] = *(const float4*)&sp[i * 4];
    }
    if (t < 64) {
        acs[t] = Acs_g[((b * NHEADS + hh) * NCHUNK + c) * 64 + t];
        dts[t] = dtb[(b * SEQ + c * 64 + t) * NHEADS + hh];
    }
    {   // stage C, B natural; X transposed (raw)
        int l = t >> 2, c0 = (t & 3) * 16;
        int row = b * SEQ + c * 64 + l;
        *(bf16x8*)&sC[l * SP + c0]      = *(const bf16x8*)&Cm[(size_t)row * DSTATE + c0];
        *(bf16x8*)&sC[l * SP + c0 + 8]  = *(const bf16x8*)&Cm[(size_t)row * DSTATE + c0 + 8];
        *(bf16x8*)&sBG[l * SP + c0]     = *(const bf16x8*)&Bm[(size_t)row * DSTATE + c0];
        *(bf16x8*)&sBG[l * SP + c0 + 8] = *(const bf16x8*)&Bm[(size_t)row * DSTATE + c0 + 8];
        bf16x8 xv0 = *(const bf16x8*)&xs[(size_t)row * DINNER + hh * 64 + c0];
        bf16x8 xv1 = *(const bf16x8*)&xs[(size_t)row * DINNER + hh * 64 + c0 + 8];
        #pragma unroll
        for (int i = 0; i < 8; i++) {
            sXS[(c0 + i) * SP + l]     = xv0[i];
            sXS[(c0 + 8 + i) * SP + l] = xv1[i];
        }
    }
    __syncthreads();
    int lane = t & 63, w = t >> 6;
    int wm = w >> 1, wn = w & 1;
    int fr = lane & 15, fc = (lane >> 4) * 8;
    // ---- m1: G0 quadrant
    f32x4 g[2][2] = {};
    #pragma unroll
    for (int kk = 0; kk < 2; kk++) {
        bf16x8 a[2], bb[2];
        #pragma unroll
        for (int i = 0; i < 2; i++)
            a[i] = *(const bf16x8*)&sC[(wm * 32 + i * 16 + fr) * SP + kk * 32 + fc];
        #pragma unroll
        for (int j = 0; j < 2; j++)
            bb[j] = *(const bf16x8*)&sBG[(wn * 32 + j * 16 + fr) * SP + kk * 32 + fc];
        #pragma unroll
        for (int i = 0; i < 2; i++)
            #pragma unroll
            for (int j = 0; j < 2; j++)
                g[i][j] = __builtin_amdgcn_mfma_f32_16x16x32_bf16(a[i], bb[j], g[i][j], 0, 0, 0);
    }
    __syncthreads();           // all m1 reads of B done
    // ---- G' = tril(G0 * exp(acs_l - acs_s)) * dt_s  (bf16, into sBG)
    #pragma unroll
    for (int i = 0; i < 2; i++) {
        #pragma unroll
        for (int j = 0; j < 2; j++) {
            int s = wn * 32 + j * 16 + (lane & 15);
            #pragma unroll
            for (int r = 0; r < 4; r++) {
                int l = wm * 32 + i * 16 + (lane >> 4) * 4 + r;
                float val = (s <= l) ? g[i][j][r] * expf(acs[l] - acs[s]) * dts[s] : 0.f;
                sBG[l * SP + s] = (bf16)val;
            }
        }
    }
    __syncthreads();           // G' visible
    // ---- m2: Y_diag = G' · X   (B-op = sXS as X^T)
    f32x4 yd[2][2] = {};
    #pragma unroll
    for (int kk = 0; kk < 2; kk++) {
        bf16x8 a[2], bb[2];
        #pragma unroll
        for (int i = 0; i < 2; i++)
            a[i] = *(const bf16x8*)&sBG[(wm * 32 + i * 16 + fr) * SP + kk * 32 + fc];
        #pragma unroll
        for (int j = 0; j < 2; j++)
            bb[j] = *(const bf16x8*)&sXS[(wn * 32 + j * 16 + fr) * SP + kk * 32 + fc];
        #pragma unroll
        for (int i = 0; i < 2; i++)
            #pragma unroll
            for (int j = 0; j < 2; j++)
                yd[i][j] = __builtin_amdgcn_mfma_f32_16x16x32_bf16(a[i], bb[j], yd[i][j], 0, 0, 0);
    }
    // raw X at output positions (for D-skip), before sXS is overwritten
    float xk[2][2][4];
    #pragma unroll
    for (int i = 0; i < 2; i++)
        #pragma unroll
        for (int j = 0; j < 2; j++) {
            int p = wn * 32 + j * 16 + (lane & 15);
            #pragma unroll
            for (int r = 0; r < 4; r++) {
                int l = wm * 32 + i * 16 + (lane >> 4) * 4 + r;
                xk[i][j][r] = (float)sXS[p * SP + l];
            }
        }
    __syncthreads();           // all sXS (X^T) reads done
    {   // overwrite sXS with S_in [p][n] (bf16)
        int p = t >> 2, n0 = (t & 3) * 16;
        const float* f = (const float*)sreg;
        bf16x8 s0, s1;
        #pragma unroll
        for (int q = 0; q < 8; q++) { s0[q] = (bf16)f[q]; s1[q] = (bf16)f[q + 8]; }
        *(bf16x8*)&sXS[p * SP + n0]     = s0;
        *(bf16x8*)&sXS[p * SP + n0 + 8] = s1;
    }
    __syncthreads();
    // ---- m3: Y_off = C · S^T
    f32x4 yo[2][2] = {};
    #pragma unroll
    for (int kk = 0; kk < 2; kk++) {
        bf16x8 a[2], bb[2];
        #pragma unroll
        for (int i = 0; i < 2; i++)
            a[i] = *(const bf16x8*)&sC[(wm * 32 + i * 16 + fr) * SP + kk * 32 + fc];
        #pragma unroll
        for (int j = 0; j < 2; j++)
            bb[j] = *(const bf16x8*)&sXS[(wn * 32 + j * 16 + fr) * SP + kk * 32 + fc];
        #pragma unroll
        for (int i = 0; i < 2; i++)
            #pragma unroll
            for (int j = 0; j < 2; j++)
                yo[i][j] = __builtin_amdgcn_mfma_f32_16x16x32_bf16(a[i], bb[j], yo[i][j], 0, 0, 0);
    }
    float Dh = Dv[hh];
    #pragma unroll
    for (int i = 0; i < 2; i++) {
        #pragma unroll
        for (int j = 0; j < 2; j++) {
            int p = wn * 32 + j * 16 + (lane & 15);
            #pragma unroll
            for (int r = 0; r < 4; r++) {
                int l = wm * 32 + i * 16 + (lane >> 4) * 4 + r;
                int row = b * SEQ + c * 64 + l;
                Y[(size_t)row * DINNER + hh * 64 + p] =
                    yd[i][j][r] + expf(acs[l]) * yo[i][j][r] + Dh * xk[i][j][r];
            }
        }
    }
}

// --------------------------------------------------- gated RMSNorm -> bf16
__global__ __launch_bounds__(256) void rms_kernel(
    const float* __restrict__ Y, const bf16* __restrict__ zx,
    const float* __restrict__ nw, bf16* __restrict__ yn) {
    int row = blockIdx.x;
    const float* yr = Y + (size_t)row * DINNER;
    const bf16* zr = zx + (size_t)row * NPAD;       // z = cols [0, 2048)
    bf16* outr = yn + (size_t)row * DINNER;
    int t = threadIdx.x;
    float vals[8];
    float ss = 0.f;
    #pragma unroll
    for (int i = 0; i < 8; i++) {
        int idx = t + i * 256;
        float z = (float)zr[idx];
        float v = yr[idx] * (z / (1.f + expf(-z)));
        vals[i] = v;
        ss += v * v;
    }
    for (int o = 32; o > 0; o >>= 1) ss += __shfl_down(ss, o);
    __shared__ float red[4];
    int wid = t >> 6, lane = t & 63;
    if (lane == 0) red[wid] = ss;
    __syncthreads();
    if (t == 0) { float a = 0; for (int i = 0; i < 4; i++) a += red[i]; red[0] = a; }
    __syncthreads();
    float r = rsqrtf(red[0] * (1.f / DINNER) + EPSF);
    #pragma unroll
    for (int i = 0; i < 8; i++) {
        int idx = t + i * 256;
        outr[idx] = (bf16)(vals[i] * r * nw[idx]);
    }
}

// ---------------------------------------------------------------------------
extern "C" void kernel_launch(void* const* d_in, const int* in_sizes, int n_in,
                              void* d_out, int out_size, void* d_ws, size_t ws_size,
                              hipStream_t stream) {
    const float* x          = (const float*)d_in[0];
    const float* ln_w       = (const float*)d_in[1];
    const float* ln_b       = (const float*)d_in[2];
    const float* in_proj_w  = (const float*)d_in[3];
    const float* conv_w     = (const float*)d_in[4];
    const float* conv_b     = (const float*)d_in[5];
    const float* dt_bias    = (const float*)d_in[6];
    const float* A_log      = (const float*)d_in[7];
    const float* Dv         = (const float*)d_in[8];
    const float* norm_w     = (const float*)d_in[9];
    const float* out_proj_w = (const float*)d_in[10];
    float* out = (float*)d_out;

    char* ws = (char*)d_ws;
    size_t off = 0;
    auto alloc = [&](size_t bytes) { char* p = ws + off; off += (bytes + 255) & ~(size_t)255; return p; };
    bf16*  h_bf  = (bf16*) alloc((size_t)4096 * DMODEL * 2);     //  8.4 MB
    bf16*  zx    = (bf16*) alloc((size_t)4096 * NPAD * 2);       // 35.6 MB
    bf16*  xs    = (bf16*) alloc((size_t)4096 * DINNER * 2);     // 16.8 MB
    float* states= (float*)alloc((size_t)2048 * 4096 * 4);       // 33.6 MB
    float* Yb    = (float*)alloc((size_t)4096 * DINNER * 4);     // 33.6 MB
    bf16*  Bt1   = (bf16*) alloc((size_t)NPAD * DMODEL * 2);     //  8.9 MB
    float* dtb   = (float*)alloc((size_t)4096 * NHEADS * 4);     //  0.5 MB
    float* Acs   = (float*)alloc((size_t)2 * NHEADS * NCHUNK * 64 * 4);
    bf16* Bm = h_bf;                          // h_bf dead after GEMM1
    bf16* Cm = h_bf + (size_t)4096 * DSTATE;
    bf16* Bt2 = Bt1;
    bf16* yn = xs;                            // xs dead after ssd_out

    ln_kernel<<<BATCH * SEQ, 256, 0, stream>>>(x, ln_w, ln_b, h_bf);

    {   // in_proj_w (1024 x 4256) -> Bt1 [4352][1024]
        dim3 g(NPAD / 32, DMODEL / 32);
        cvt_w_kernel<<<g, 256, 0, stream>>>(in_proj_w, Bt1, DMODEL, DINPROJ, NPAD);
    }
    {   // zx = h @ in_proj_w   (bf16 out)
        dim3 g(NPAD / 128, (BATCH * SEQ) / 128);
        gemm_bf16_pipe<128, 128, bf16><<<g, 256, 0, stream>>>(
            h_bf, Bt1, zx, BATCH * SEQ, NPAD, DMODEL, nullptr);
    }

    conv_kernel<<<(BATCH * SEQ * CONVDIM) / 256, 256, 0, stream>>>(
        zx, conv_w, conv_b, xs, Bm, Cm);

    dt_kernel<<<(BATCH * SEQ * NHEADS) / 256, 256, 0, stream>>>(zx, dt_bias, dtb);

    ssd_states_kernel<<<BATCH * NCHUNK * NHEADS, 256, 0, stream>>>(
        xs, Bm, dtb, A_log, states, Acs);

    ssd_scan_kernel<<<BATCH * NHEADS * 8, 256, 0, stream>>>(states, Acs);

    ssd_out_kernel<<<BATCH * NCHUNK * NHEADS, 256, 0, stream>>>(
        xs, Bm, Cm, dtb, states, Acs, Dv, Yb);

    rms_kernel<<<BATCH * SEQ, 256, 0, stream>>>(Yb, zx, norm_w, yn);

    {   // out_proj_w (2048 x 1024) -> Bt2 [1024][2048]
        dim3 g(DMODEL / 32, DINNER / 32);
        cvt_w_kernel<<<g, 256, 0, stream>>>(out_proj_w, Bt2, DINNER, DMODEL, DMODEL);
    }
    {   // out = yn @ out_proj_w + x   (128x64 tiles -> 512 blocks)
        dim3 g(DMODEL / 64, (BATCH * SEQ) / 128);
        gemm_bf16_pipe<128, 64, float><<<g, 256, 0, stream>>>(
            yn, Bt2, out, BATCH * SEQ, DMODEL, DINNER, x);
    }
}

// Round 6
// 206.914 us; speedup vs baseline: 4.9303x; 1.0613x over previous
//
#include <hip/hip_runtime.h>
#include <hip/hip_bf16.h>

#define BATCH   2
#define SEQ     2048
#define DMODEL  1024
#define DINNER  2048
#define DSTATE  64
#define NHEADS  32
#define HEADDIM 64
#define CONVDIM 2176
#define DINPROJ 4256
#define NPAD    4352        // DINPROJ padded to 34*128 for the MFMA GEMM
#define NCHUNK  32          // SEQ / 64
#define EPSF    1e-5f
#define SP      88          // LDS row stride (bf16): 176B = 16B-aligned, ~2-way conflicts
#define CDT     (CONVDIM + NHEADS)   // 2208: conv channels + dt heads, fused kernel

typedef __bf16 bf16;
typedef bf16  bf16x4 __attribute__((ext_vector_type(4)));
typedef bf16  bf16x8 __attribute__((ext_vector_type(8)));
typedef float f32x4  __attribute__((ext_vector_type(4)));

__device__ __forceinline__ void gll16(const bf16* g, bf16* l) {
    __builtin_amdgcn_global_load_lds(
        (const __attribute__((address_space(1))) void*)g,
        (__attribute__((address_space(3))) void*)l, 16, 0, 0);
}

// ---------------------------------------------------------------- LayerNorm -> bf16
__global__ __launch_bounds__(256) void ln_kernel(
    const float* __restrict__ x, const float* __restrict__ w,
    const float* __restrict__ bv, bf16* __restrict__ h) {
    int row = blockIdx.x;                    // 4096 rows
    const float* xr = x + (size_t)row * DMODEL;
    bf16* hr = h + (size_t)row * DMODEL;
    int t = threadIdx.x;
    float4 v = ((const float4*)xr)[t];
    float s  = v.x + v.y + v.z + v.w;
    float ss = v.x*v.x + v.y*v.y + v.z*v.z + v.w*v.w;
    for (int o = 32; o > 0; o >>= 1) { s += __shfl_down(s, o); ss += __shfl_down(ss, o); }
    __shared__ float red[2][4];
    int wid = t >> 6, lane = t & 63;
    if (lane == 0) { red[0][wid] = s; red[1][wid] = ss; }
    __syncthreads();
    if (t == 0) {
        float a = 0, b2 = 0;
        for (int i = 0; i < 4; i++) { a += red[0][i]; b2 += red[1][i]; }
        red[0][0] = a; red[1][0] = b2;
    }
    __syncthreads();
    float mean = red[0][0] * (1.f / DMODEL);
    float var  = red[1][0] * (1.f / DMODEL) - mean * mean;
    float rstd = rsqrtf(var + EPSF);
    for (int i = t; i < DMODEL; i += 256)
        hr[i] = (bf16)((xr[i] - mean) * rstd * w[i] + bv[i]);
}

// ---------------- both weight transposes (+bf16 cast, +pad) in ONE launch
// W1: in_proj 1024x4256 -> Bt1[4352][1024]; W2: out_proj 2048x1024 -> Bt2[1024][2048]
__global__ __launch_bounds__(256) void cvt_w_both_kernel(
    const float* __restrict__ W1, const float* __restrict__ W2,
    bf16* __restrict__ Bt1, bf16* __restrict__ Bt2) {
    __shared__ float sm[32][33];
    int bid = blockIdx.x;
    const float* W; bf16* Bt; int K, N, NP, bx, by;
    if (bid < 4352) {            // W1: 136 x 32 tile-grid
        W = W1; Bt = Bt1; K = 1024; N = 4256; NP = 4352;
        bx = bid % 136; by = bid / 136;
    } else {                     // W2: 32 x 64 tile-grid
        int b2 = bid - 4352;
        W = W2; Bt = Bt2; K = 2048; N = 1024; NP = 1024;
        bx = b2 % 32; by = b2 / 32;
    }
    int n0 = bx * 32, k0 = by * 32;
    int tx = threadIdx.x & 31, ty = threadIdx.x >> 5;   // 32 x 8
    for (int i = 0; i < 4; i++) {
        int k = k0 + ty + i * 8, n = n0 + tx;
        sm[ty + i * 8][tx] = (n < N) ? W[(size_t)k * N + n] : 0.f;
    }
    __syncthreads();
    for (int i = 0; i < 4; i++) {
        int n = n0 + ty + i * 8, k = k0 + tx;
        if (n < NP) Bt[(size_t)n * K + k] = (bf16)sm[tx][ty + i * 8];
    }
}

// ------------------------------------------- bf16 MFMA GEMM, 2-phase pipelined
template<int BM, int BN, typename OUT_T>
__global__ __launch_bounds__(256) void gemm_bf16_pipe(
    const bf16* __restrict__ A, const bf16* __restrict__ Bt,
    OUT_T* __restrict__ C, int M, int N, int K,
    const float* __restrict__ resid) {
    constexpr int MR = BM / 32;
    constexpr int NR = BN / 32;
    __shared__ __align__(16) bf16 sA[2][BM * 32];
    __shared__ __align__(16) bf16 sB[2][BN * 32];
    int t = threadIdx.x;
    int lane = t & 63, w = t >> 6;
    int m0 = blockIdx.y * BM, n0 = blockIdx.x * BN;
    int wm = w >> 1, wn = w & 1;
    f32x4 acc[MR][NR] = {};
    int srow = w * 16 + (lane >> 2);
    int scol = (lane & 3) * 8;
    int fr = lane & 15;
    int fc = (lane >> 4) * 8;
    auto stage = [&](int buf, int k0) {
        #pragma unroll
        for (int i = 0; i < BM / 64; i++)
            gll16(&A[(size_t)(m0 + i * 64 + srow) * K + k0 + scol],
                  &sA[buf][(i * 64 + w * 16) * 32]);
        #pragma unroll
        for (int i = 0; i < BN / 64; i++)
            gll16(&Bt[(size_t)(n0 + i * 64 + srow) * K + k0 + scol],
                  &sB[buf][(i * 64 + w * 16) * 32]);
    };
    int nt = K / 32;
    stage(0, 0);
    __syncthreads();
    int cur = 0;
    for (int tt = 0; tt < nt; tt++) {
        if (tt + 1 < nt) stage(cur ^ 1, (tt + 1) * 32);
        bf16x8 af[MR], bfr[NR];
        #pragma unroll
        for (int i = 0; i < MR; i++)
            af[i] = *(const bf16x8*)&sA[cur][(wm * (BM/2) + i * 16 + fr) * 32 + fc];
        #pragma unroll
        for (int j = 0; j < NR; j++)
            bfr[j] = *(const bf16x8*)&sB[cur][(wn * (BN/2) + j * 16 + fr) * 32 + fc];
        #pragma unroll
        for (int i = 0; i < MR; i++)
            #pragma unroll
            for (int j = 0; j < NR; j++)
                acc[i][j] = __builtin_amdgcn_mfma_f32_16x16x32_bf16(
                    af[i], bfr[j], acc[i][j], 0, 0, 0);
        __syncthreads();
        cur ^= 1;
    }
    #pragma unroll
    for (int i = 0; i < MR; i++) {
        #pragma unroll
        for (int j = 0; j < NR; j++) {
            int col = n0 + wn * (BN/2) + j * 16 + (lane & 15);
            #pragma unroll
            for (int r = 0; r < 4; r++) {
                int row = m0 + wm * (BM/2) + i * 16 + (lane >> 4) * 4 + r;
                float v = acc[i][j][r];
                if (resid) v += resid[(size_t)row * N + col];
                C[(size_t)row * N + col] = (OUT_T)v;
            }
        }
    }
}

// ------------------------- causal depthwise conv + SiLU, fused with dt softplus
// channels [0, CONVDIM): conv; [CONVDIM, CONVDIM+NHEADS): softplus(dt + bias).
__global__ __launch_bounds__(256) void convdt_kernel(
    const bf16* __restrict__ zx, const float* __restrict__ cw,
    const float* __restrict__ cb, const float* __restrict__ dt_bias,
    bf16* __restrict__ xs, bf16* __restrict__ Bm, bf16* __restrict__ Cm,
    float* __restrict__ dtb) {
    int idx = blockIdx.x * 256 + threadIdx.x;        // b*l*CDT
    int ch = idx % CDT;
    int bl = idx / CDT;
    if (ch >= CONVDIM) {                             // dt path
        int hh = ch - CONVDIM;
        float v = (float)zx[(size_t)bl * NPAD + DINNER + ch] + dt_bias[hh];
        dtb[bl * NHEADS + hh] = (v > 20.f) ? v : log1pf(expf(v));
        return;
    }
    int b = bl / SEQ, tt = bl % SEQ;
    float acc = cb[ch];
    #pragma unroll
    for (int k = 0; k < 4; k++) {
        int tp = tt - 3 + k;
        if (tp >= 0)
            acc += (float)zx[(size_t)(b * SEQ + tp) * NPAD + DINNER + ch] * cw[ch * 4 + k];
    }
    float s = acc / (1.f + expf(-acc));
    if (ch < DINNER)              xs[(size_t)bl * DINNER + ch] = (bf16)s;
    else if (ch < DINNER+DSTATE)  Bm[bl * DSTATE + (ch - DINNER)] = (bf16)s;
    else                          Cm[bl * DSTATE + (ch - DINNER - DSTATE)] = (bf16)s;
}

// ----------------------------------------- SSD: per-chunk local states (MFMA)
// states[p][n] = sum_l (X[l][p]*dt[l]) * (B[l][n]*exp(alast-acs[l]))  -> bf16
__global__ __launch_bounds__(256) void ssd_states_kernel(
    const bf16* __restrict__ xs, const bf16* __restrict__ Bm,
    const float* __restrict__ dtb, const float* __restrict__ A_log,
    bf16* __restrict__ states, float* __restrict__ Acs_g) {
    int blk = blockIdx.x;
    int hh = blk % NHEADS;
    int bc = blk / NHEADS;
    int c = bc % NCHUNK, b = bc / NCHUNK;
    __shared__ __align__(16) bf16 sXT[64 * SP];   // [p][l]
    __shared__ __align__(16) bf16 sBT[64 * SP];   // [n][l]
    __shared__ float dts[64], acs[64];
    int t = threadIdx.x;
    float Ah = -expf(A_log[hh]);
    if (t < 64) {                                // wave 0: load + parallel scan
        float dv = dtb[(b * SEQ + c * 64 + t) * NHEADS + hh];
        float v = dv * Ah;
        #pragma unroll
        for (int o = 1; o < 64; o <<= 1) {
            float p = __shfl_up(v, o);
            if (t >= o) v += p;
        }
        dts[t] = dv; acs[t] = v;
        Acs_g[((b * NHEADS + hh) * NCHUNK + c) * 64 + t] = v;
    }
    __syncthreads();
    float alast = acs[63];
    {   // stage transposed, weighted
        int l = t >> 2, c0 = (t & 3) * 16;
        int row = b * SEQ + c * 64 + l;
        float dl = dts[l];
        float wl = expf(alast - acs[l]);
        bf16x8 xv0 = *(const bf16x8*)&xs[(size_t)row * DINNER + hh * 64 + c0];
        bf16x8 xv1 = *(const bf16x8*)&xs[(size_t)row * DINNER + hh * 64 + c0 + 8];
        bf16x8 bv0 = *(const bf16x8*)&Bm[(size_t)row * DSTATE + c0];
        bf16x8 bv1 = *(const bf16x8*)&Bm[(size_t)row * DSTATE + c0 + 8];
        #pragma unroll
        for (int i = 0; i < 8; i++) {
            sXT[(c0 + i) * SP + l]     = (bf16)((float)xv0[i] * dl);
            sXT[(c0 + 8 + i) * SP + l] = (bf16)((float)xv1[i] * dl);
            sBT[(c0 + i) * SP + l]     = (bf16)((float)bv0[i] * wl);
            sBT[(c0 + 8 + i) * SP + l] = (bf16)((float)bv1[i] * wl);
        }
    }
    __syncthreads();
    int lane = t & 63, w = t >> 6;
    int wm = w >> 1, wn = w & 1;
    int fr = lane & 15, fc = (lane >> 4) * 8;
    f32x4 acc[2][2] = {};
    #pragma unroll
    for (int kk = 0; kk < 2; kk++) {
        bf16x8 a[2], bb[2];
        #pragma unroll
        for (int i = 0; i < 2; i++)
            a[i] = *(const bf16x8*)&sXT[(wm * 32 + i * 16 + fr) * SP + kk * 32 + fc];
        #pragma unroll
        for (int j = 0; j < 2; j++)
            bb[j] = *(const bf16x8*)&sBT[(wn * 32 + j * 16 + fr) * SP + kk * 32 + fc];
        #pragma unroll
        for (int i = 0; i < 2; i++)
            #pragma unroll
            for (int j = 0; j < 2; j++)
                acc[i][j] = __builtin_amdgcn_mfma_f32_16x16x32_bf16(
                    a[i], bb[j], acc[i][j], 0, 0, 0);
    }
    bf16* outp = states + (size_t)blk * 4096;
    #pragma unroll
    for (int i = 0; i < 2; i++)
        #pragma unroll
        for (int j = 0; j < 2; j++)
            #pragma unroll
            for (int r = 0; r < 4; r++)
                outp[(wm*32 + i*16 + (lane>>4)*4 + r) * 64 + wn*32 + j*16 + (lane&15)]
                    = (bf16)acc[i][j][r];
}

// ------------------------------------------- SSD: inter-chunk sequential scan
// bf16 in-place: slot c becomes ENTERING state for chunk c. fp32 carry.
// grid = BATCH*NHEADS*4; each block owns a 1024-element slice (4 elems/thread).
__global__ __launch_bounds__(256) void ssd_scan_kernel(
    bf16* __restrict__ states, const float* __restrict__ Acs_g) {
    int bid = blockIdx.x;
    int slice = bid & 3, bh = bid >> 2;
    int hh = bh % NHEADS, b = bh / NHEADS;
    int e0 = slice * 1024 + threadIdx.x * 4;
    bf16x4 loc[NCHUNK];
    float dec[NCHUNK];
    #pragma unroll
    for (int c = 0; c < NCHUNK; c++) {
        loc[c] = *(const bf16x4*)&states[(size_t)((b*NCHUNK+c)*NHEADS+hh)*4096 + e0];
        dec[c] = expf(Acs_g[((b*NHEADS+hh)*NCHUNK + c)*64 + 63]);
    }
    float S0 = 0.f, S1 = 0.f, S2 = 0.f, S3 = 0.f;
    #pragma unroll
    for (int c = 0; c < NCHUNK; c++) {
        bf16x4 l = loc[c];
        bf16x4 o; o[0] = (bf16)S0; o[1] = (bf16)S1; o[2] = (bf16)S2; o[3] = (bf16)S3;
        *(bf16x4*)&states[(size_t)((b*NCHUNK+c)*NHEADS+hh)*4096 + e0] = o;
        S0 = dec[c]*S0 + (float)l[0];
        S1 = dec[c]*S1 + (float)l[1];
        S2 = dec[c]*S2 + (float)l[2];
        S3 = dec[c]*S3 + (float)l[3];
    }
}

// --------------------------------- SSD: Y = Y_diag + Y_off + D*X (MFMA) -> bf16
__global__ __launch_bounds__(256) void ssd_out_kernel(
    const bf16* __restrict__ xs, const bf16* __restrict__ Bm,
    const bf16* __restrict__ Cm, const float* __restrict__ dtb,
    const bf16* __restrict__ states, const float* __restrict__ Acs_g,
    const float* __restrict__ Dv, bf16* __restrict__ Y) {
    int blk = blockIdx.x;
    int hh = blk % NHEADS;
    int bc = blk / NHEADS;
    int c = bc % NCHUNK, b = bc / NCHUNK;
    __shared__ __align__(16) bf16 sC [64 * SP];   // [l][n]
    __shared__ __align__(16) bf16 sBG[64 * SP];   // B[s][n] -> G'[l][s]
    __shared__ __align__(16) bf16 sXS[64 * SP];   // X^T[p][l] -> S[p][n]
    __shared__ float acs[64], dts[64];
    int t = threadIdx.x;
    bf16x8 sreg0, sreg1;                          // T14: S prefetch to regs
    {
        const bf16* sp = states + (size_t)blk * 4096 + t * 16;
        sreg0 = *(const bf16x8*)&sp[0];
        sreg1 = *(const bf16x8*)&sp[8];
    }
    if (t < 64) {
        acs[t] = Acs_g[((b * NHEADS + hh) * NCHUNK + c) * 64 + t];
        dts[t] = dtb[(b * SEQ + c * 64 + t) * NHEADS + hh];
    }
    {   // stage C, B natural; X transposed (raw)
        int l = t >> 2, c0 = (t & 3) * 16;
        int row = b * SEQ + c * 64 + l;
        *(bf16x8*)&sC[l * SP + c0]      = *(const bf16x8*)&Cm[(size_t)row * DSTATE + c0];
        *(bf16x8*)&sC[l * SP + c0 + 8]  = *(const bf16x8*)&Cm[(size_t)row * DSTATE + c0 + 8];
        *(bf16x8*)&sBG[l * SP + c0]     = *(const bf16x8*)&Bm[(size_t)row * DSTATE + c0];
        *(bf16x8*)&sBG[l * SP + c0 + 8] = *(const bf16x8*)&Bm[(size_t)row * DSTATE + c0 + 8];
        bf16x8 xv0 = *(const bf16x8*)&xs[(size_t)row * DINNER + hh * 64 + c0];
        bf16x8 xv1 = *(const bf16x8*)&xs[(size_t)row * DINNER + hh * 64 + c0 + 8];
        #pragma unroll
        for (int i = 0; i < 8; i++) {
            sXS[(c0 + i) * SP + l]     = xv0[i];
            sXS[(c0 + 8 + i) * SP + l] = xv1[i];
        }
    }
    __syncthreads();
    int lane = t & 63, w = t >> 6;
    int wm = w >> 1, wn = w & 1;
    int fr = lane & 15, fc = (lane >> 4) * 8;
    // ---- m1: G0 = C . B^T
    f32x4 g[2][2] = {};
    #pragma unroll
    for (int kk = 0; kk < 2; kk++) {
        bf16x8 a[2], bb[2];
        #pragma unroll
        for (int i = 0; i < 2; i++)
            a[i] = *(const bf16x8*)&sC[(wm * 32 + i * 16 + fr) * SP + kk * 32 + fc];
        #pragma unroll
        for (int j = 0; j < 2; j++)
            bb[j] = *(const bf16x8*)&sBG[(wn * 32 + j * 16 + fr) * SP + kk * 32 + fc];
        #pragma unroll
        for (int i = 0; i < 2; i++)
            #pragma unroll
            for (int j = 0; j < 2; j++)
                g[i][j] = __builtin_amdgcn_mfma_f32_16x16x32_bf16(a[i], bb[j], g[i][j], 0, 0, 0);
    }
    __syncthreads();           // all m1 reads of B done
    // ---- G' = tril(G0 * exp(acs_l - acs_s)) * dt_s
    #pragma unroll
    for (int i = 0; i < 2; i++) {
        #pragma unroll
        for (int j = 0; j < 2; j++) {
            int s = wn * 32 + j * 16 + (lane & 15);
            #pragma unroll
            for (int r = 0; r < 4; r++) {
                int l = wm * 32 + i * 16 + (lane >> 4) * 4 + r;
                float val = (s <= l) ? g[i][j][r] * expf(acs[l] - acs[s]) * dts[s] : 0.f;
                sBG[l * SP + s] = (bf16)val;
            }
        }
    }
    __syncthreads();           // G' visible
    // ---- m2: Y_diag = G' . X
    f32x4 yd[2][2] = {};
    #pragma unroll
    for (int kk = 0; kk < 2; kk++) {
        bf16x8 a[2], bb[2];
        #pragma unroll
        for (int i = 0; i < 2; i++)
            a[i] = *(const bf16x8*)&sBG[(wm * 32 + i * 16 + fr) * SP + kk * 32 + fc];
        #pragma unroll
        for (int j = 0; j < 2; j++)
            bb[j] = *(const bf16x8*)&sXS[(wn * 32 + j * 16 + fr) * SP + kk * 32 + fc];
        #pragma unroll
        for (int i = 0; i < 2; i++)
            #pragma unroll
            for (int j = 0; j < 2; j++)
                yd[i][j] = __builtin_amdgcn_mfma_f32_16x16x32_bf16(a[i], bb[j], yd[i][j], 0, 0, 0);
    }
    // raw X at output positions (D-skip), before sXS is overwritten
    float xk[2][2][4];
    #pragma unroll
    for (int i = 0; i < 2; i++)
        #pragma unroll
        for (int j = 0; j < 2; j++) {
            int p = wn * 32 + j * 16 + (lane & 15);
            #pragma unroll
            for (int r = 0; r < 4; r++) {
                int l = wm * 32 + i * 16 + (lane >> 4) * 4 + r;
                xk[i][j][r] = (float)sXS[p * SP + l];
            }
        }
    __syncthreads();           // all sXS (X^T) reads done
    {   // overwrite sXS with S_in [p][n]
        int p = t >> 2, n0 = (t & 3) * 16;
        *(bf16x8*)&sXS[p * SP + n0]     = sreg0;
        *(bf16x8*)&sXS[p * SP + n0 + 8] = sreg1;
    }
    __syncthreads();
    // ---- m3: Y_off = C . S^T
    f32x4 yo[2][2] = {};
    #pragma unroll
    for (int kk = 0; kk < 2; kk++) {
        bf16x8 a[2], bb[2];
        #pragma unroll
        for (int i = 0; i < 2; i++)
            a[i] = *(const bf16x8*)&sC[(wm * 32 + i * 16 + fr) * SP + kk * 32 + fc];
        #pragma unroll
        for (int j = 0; j < 2; j++)
            bb[j] = *(const bf16x8*)&sXS[(wn * 32 + j * 16 + fr) * SP + kk * 32 + fc];
        #pragma unroll
        for (int i = 0; i < 2; i++)
            #pragma unroll
            for (int j = 0; j < 2; j++)
                yo[i][j] = __builtin_amdgcn_mfma_f32_16x16x32_bf16(a[i], bb[j], yo[i][j], 0, 0, 0);
    }
    float Dh = Dv[hh];
    #pragma unroll
    for (int i = 0; i < 2; i++) {
        #pragma unroll
        for (int j = 0; j < 2; j++) {
            int p = wn * 32 + j * 16 + (lane & 15);
            #pragma unroll
            for (int r = 0; r < 4; r++) {
                int l = wm * 32 + i * 16 + (lane >> 4) * 4 + r;
                int row = b * SEQ + c * 64 + l;
                Y[(size_t)row * DINNER + hh * 64 + p] =
                    (bf16)(yd[i][j][r] + expf(acs[l]) * yo[i][j][r] + Dh * xk[i][j][r]);
            }
        }
    }
}

// --------------------------------------------------- gated RMSNorm -> bf16
__global__ __launch_bounds__(256) void rms_kernel(
    const bf16* __restrict__ Y, const bf16* __restrict__ zx,
    const float* __restrict__ nw, bf16* __restrict__ yn) {
    int row = blockIdx.x;
    const bf16* yr = Y + (size_t)row * DINNER;
    const bf16* zr = zx + (size_t)row * NPAD;       // z = cols [0, 2048)
    bf16* outr = yn + (size_t)row * DINNER;
    int t = threadIdx.x;
    float vals[8];
    float ss = 0.f;
    #pragma unroll
    for (int i = 0; i < 8; i++) {
        int idx = t + i * 256;
        float z = (float)zr[idx];
        float v = (float)yr[idx] * (z / (1.f + expf(-z)));
        vals[i] = v;
        ss += v * v;
    }
    for (int o = 32; o > 0; o >>= 1) ss += __shfl_down(ss, o);
    __shared__ float red[4];
    int wid = t >> 6, lane = t & 63;
    if (lane == 0) red[wid] = ss;
    __syncthreads();
    if (t == 0) { float a = 0; for (int i = 0; i < 4; i++) a += red[i]; red[0] = a; }
    __syncthreads();
    float r = rsqrtf(red[0] * (1.f / DINNER) + EPSF);
    #pragma unroll
    for (int i = 0; i < 8; i++) {
        int idx = t + i * 256;
        outr[idx] = (bf16)(vals[i] * r * nw[idx]);
    }
}

// ---------------------------------------------------------------------------
extern "C" void kernel_launch(void* const* d_in, const int* in_sizes, int n_in,
                              void* d_out, int out_size, void* d_ws, size_t ws_size,
                              hipStream_t stream) {
    const float* x          = (const float*)d_in[0];
    const float* ln_w       = (const float*)d_in[1];
    const float* ln_b       = (const float*)d_in[2];
    const float* in_proj_w  = (const float*)d_in[3];
    const float* conv_w     = (const float*)d_in[4];
    const float* conv_b     = (const float*)d_in[5];
    const float* dt_bias    = (const float*)d_in[6];
    const float* A_log      = (const float*)d_in[7];
    const float* Dv         = (const float*)d_in[8];
    const float* norm_w     = (const float*)d_in[9];
    const float* out_proj_w = (const float*)d_in[10];
    float* out = (float*)d_out;

    char* ws = (char*)d_ws;
    size_t off = 0;
    auto alloc = [&](size_t bytes) { char* p = ws + off; off += (bytes + 255) & ~(size_t)255; return p; };
    bf16*  h_bf  = (bf16*) alloc((size_t)4096 * DMODEL * 2);     //  8.4 MB
    bf16*  zx    = (bf16*) alloc((size_t)4096 * NPAD * 2);       // 35.6 MB
    bf16*  xs    = (bf16*) alloc((size_t)4096 * DINNER * 2);     // 16.8 MB
    bf16*  states= (bf16*) alloc((size_t)2048 * 4096 * 2);       // 16.8 MB
    bf16*  Yb    = (bf16*) alloc((size_t)4096 * DINNER * 2);     // 16.8 MB
    bf16*  Bt1   = (bf16*) alloc((size_t)NPAD * DMODEL * 2);     //  8.9 MB
    bf16*  Bt2   = (bf16*) alloc((size_t)DMODEL * DINNER * 2);   //  4.2 MB
    float* dtb   = (float*)alloc((size_t)4096 * NHEADS * 4);     //  0.5 MB
    float* Acs   = (float*)alloc((size_t)2 * NHEADS * NCHUNK * 64 * 4);
    bf16* Bm = h_bf;                          // h_bf dead after GEMM1
    bf16* Cm = h_bf + (size_t)4096 * DSTATE;
    bf16* yn = xs;                            // xs dead after ssd_out

    // both weight transposes first (independent of everything else)
    cvt_w_both_kernel<<<4352 + 2048, 256, 0, stream>>>(in_proj_w, out_proj_w, Bt1, Bt2);

    ln_kernel<<<BATCH * SEQ, 256, 0, stream>>>(x, ln_w, ln_b, h_bf);

    {   // zx = h @ in_proj_w   (bf16 out)
        dim3 g(NPAD / 128, (BATCH * SEQ) / 128);
        gemm_bf16_pipe<128, 128, bf16><<<g, 256, 0, stream>>>(
            h_bf, Bt1, zx, BATCH * SEQ, NPAD, DMODEL, nullptr);
    }

    convdt_kernel<<<(BATCH * SEQ * CDT) / 256, 256, 0, stream>>>(
        zx, conv_w, conv_b, dt_bias, xs, Bm, Cm, dtb);

    ssd_states_kernel<<<BATCH * NCHUNK * NHEADS, 256, 0, stream>>>(
        xs, Bm, dtb, A_log, states, Acs);

    ssd_scan_kernel<<<BATCH * NHEADS * 4, 256, 0, stream>>>(states, Acs);

    ssd_out_kernel<<<BATCH * NCHUNK * NHEADS, 256, 0, stream>>>(
        xs, Bm, Cm, dtb, states, Acs, Dv, Yb);

    rms_kernel<<<BATCH * SEQ, 256, 0, stream>>>(Yb, zx, norm_w, yn);

    {   // out = yn @ out_proj_w + x   (128x64 tiles -> 512 blocks)
        dim3 g(DMODEL / 64, (BATCH * SEQ) / 128);
        gemm_bf16_pipe<128, 64, float><<<g, 256, 0, stream>>>(
            yn, Bt2, out, BATCH * SEQ, DMODEL, DINNER, x);
    }
}

// Round 7
// 198.222 us; speedup vs baseline: 5.1465x; 1.0439x over previous
//
#include <hip/hip_runtime.h>
#include <hip/hip_bf16.h>

#define BATCH   2
#define SEQ     2048
#define DMODEL  1024
#define DINNER  2048
#define DSTATE  64
#define NHEADS  32
#define HEADDIM 64
#define CONVDIM 2176
#define DINPROJ 4256
#define NPAD    4352        // DINPROJ padded to 34*128 for the MFMA GEMM
#define NCHUNK  32          // SEQ / 64
#define EPSF    1e-5f
#define SP      88          // LDS row stride (bf16) for SSD kernels
#define CDT     (CONVDIM + NHEADS)   // 2208: conv channels + dt heads

typedef __bf16 bf16;
typedef bf16  bf16x4 __attribute__((ext_vector_type(4)));
typedef bf16  bf16x8 __attribute__((ext_vector_type(8)));
typedef float f32x4  __attribute__((ext_vector_type(4)));

template<int V> struct IC { static constexpr int value = V; };

__device__ __forceinline__ void gll16(const bf16* g, bf16* l) {
    __builtin_amdgcn_global_load_lds(
        (const __attribute__((address_space(1))) void*)g,
        (__attribute__((address_space(3))) void*)l, 16, 0, 0);
}

template<int VM> __device__ __forceinline__ void vmwait() {
    if constexpr (VM == 0) asm volatile("s_waitcnt vmcnt(0)" ::: "memory");
    if constexpr (VM == 3) asm volatile("s_waitcnt vmcnt(3)" ::: "memory");
    if constexpr (VM == 4) asm volatile("s_waitcnt vmcnt(4)" ::: "memory");
    if constexpr (VM == 6) asm volatile("s_waitcnt vmcnt(6)" ::: "memory");
    if constexpr (VM == 8) asm volatile("s_waitcnt vmcnt(8)" ::: "memory");
}

// ------------- preprocessing: weight transposes (+bf16) AND LayerNorm, one launch
// blocks [0,4352): W1 tiles; [4352,6400): W2 tiles; [6400,10496): LN rows.
__global__ __launch_bounds__(256) void pre_kernel(
    const float* __restrict__ x, const float* __restrict__ lw,
    const float* __restrict__ lb, bf16* __restrict__ h,
    const float* __restrict__ W1, const float* __restrict__ W2,
    bf16* __restrict__ Bt1, bf16* __restrict__ Bt2) {
    __shared__ float sm[32][33];
    int bid = blockIdx.x;
    int t = threadIdx.x;
    if (bid < 6400) {            // weight transpose path
        const float* W; bf16* Bt; int K, N, NP, bx, by;
        if (bid < 4352) {        // W1: 136 x 32 tile-grid
            W = W1; Bt = Bt1; K = 1024; N = 4256; NP = 4352;
            bx = bid % 136; by = bid / 136;
        } else {                 // W2: 32 x 64 tile-grid
            int b2 = bid - 4352;
            W = W2; Bt = Bt2; K = 2048; N = 1024; NP = 1024;
            bx = b2 % 32; by = b2 / 32;
        }
        int n0 = bx * 32, k0 = by * 32;
        int tx = t & 31, ty = t >> 5;   // 32 x 8
        for (int i = 0; i < 4; i++) {
            int k = k0 + ty + i * 8, n = n0 + tx;
            sm[ty + i * 8][tx] = (n < N) ? W[(size_t)k * N + n] : 0.f;
        }
        __syncthreads();
        for (int i = 0; i < 4; i++) {
            int n = n0 + ty + i * 8, k = k0 + tx;
            if (n < NP) Bt[(size_t)n * K + k] = (bf16)sm[tx][ty + i * 8];
        }
        return;
    }
    // LayerNorm path
    int row = bid - 6400;
    const float* xr = x + (size_t)row * DMODEL;
    bf16* hr = h + (size_t)row * DMODEL;
    float4 v = ((const float4*)xr)[t];
    float s  = v.x + v.y + v.z + v.w;
    float ss = v.x*v.x + v.y*v.y + v.z*v.z + v.w*v.w;
    for (int o = 32; o > 0; o >>= 1) { s += __shfl_down(s, o); ss += __shfl_down(ss, o); }
    int wid = t >> 6, lane = t & 63;
    if (lane == 0) { sm[0][wid] = s; sm[1][wid] = ss; }
    __syncthreads();
    if (t == 0) {
        float a = 0, b2 = 0;
        for (int i = 0; i < 4; i++) { a += sm[0][i]; b2 += sm[1][i]; }
        sm[0][0] = a; sm[1][0] = b2;
    }
    __syncthreads();
    float mean = sm[0][0] * (1.f / DMODEL);
    float var  = sm[1][0] * (1.f / DMODEL) - mean * mean;
    float rstd = rsqrtf(var + EPSF);
    for (int i = t; i < DMODEL; i += 256)
        hr[i] = (bf16)((xr[i] - mean) * rstd * lw[i] + lb[i]);
}

// ---------------- bf16 MFMA GEMM, 3-deep ring pipeline (T4 counted vmcnt)
// C[M][N] = A[M][K] @ Bt[N][K]^T (+resid). BK=32; loads span 3 K-steps; raw
// s_barrier + counted vmcnt (never 0 in steady state). LPT = gll16 per thread
// per tile; steady-state outstanding = 3*LPT, wait at 2*LPT.
template<int BM, int BN, typename OUT_T>
__global__ __launch_bounds__(256) void gemm_bf16_pipe3(
    const bf16* __restrict__ A, const bf16* __restrict__ Bt,
    OUT_T* __restrict__ C, int M, int N, int K,
    const float* __restrict__ resid) {
    constexpr int MR = BM / 32;
    constexpr int NR = BN / 32;
    constexpr int LPT = BM / 64 + BN / 64;   // gll16 per thread per tile
    __shared__ __align__(16) bf16 sA[3][BM * 32];
    __shared__ __align__(16) bf16 sB[3][BN * 32];
    int t = threadIdx.x;
    int lane = t & 63, w = t >> 6;
    int m0 = blockIdx.y * BM, n0 = blockIdx.x * BN;
    int wm = w >> 1, wn = w & 1;
    f32x4 acc[MR][NR] = {};
    int srow = w * 16 + (lane >> 2);
    int scol = (lane & 3) * 8;
    int fr = lane & 15;
    int fc = (lane >> 4) * 8;
    auto stage = [&](int buf, int k0) {
        #pragma unroll
        for (int i = 0; i < BM / 64; i++)
            gll16(&A[(size_t)(m0 + i * 64 + srow) * K + k0 + scol],
                  &sA[buf][(i * 64 + w * 16) * 32]);
        #pragma unroll
        for (int i = 0; i < BN / 64; i++)
            gll16(&Bt[(size_t)(n0 + i * 64 + srow) * K + k0 + scol],
                  &sB[buf][(i * 64 + w * 16) * 32]);
    };
    int nt = K / 32;
    stage(0, 0); stage(1, 32); stage(2, 64);     // 3 tiles in flight
    int tt = 0;
    auto iter = [&](auto vmtag) {
        constexpr int VM = decltype(vmtag)::value;
        vmwait<VM>();                            // own tile-tt loads landed
        __builtin_amdgcn_s_barrier();            // ...for ALL waves -> buf ready
        int buf = tt % 3;
        bf16x8 af[MR], bfr[NR];
        #pragma unroll
        for (int i = 0; i < MR; i++)
            af[i] = *(const bf16x8*)&sA[buf][(wm * (BM/2) + i * 16 + fr) * 32 + fc];
        #pragma unroll
        for (int j = 0; j < NR; j++)
            bfr[j] = *(const bf16x8*)&sB[buf][(wn * (BN/2) + j * 16 + fr) * 32 + fc];
        asm volatile("s_waitcnt lgkmcnt(0)" ::: "memory");   // reads returned
        __builtin_amdgcn_sched_barrier(0);
        __builtin_amdgcn_s_barrier();            // all waves done reading buf
        if (tt + 3 < nt) stage(buf, (tt + 3) * 32);          // reuse ring slot
        #pragma unroll
        for (int i = 0; i < MR; i++)
            #pragma unroll
            for (int j = 0; j < NR; j++)
                acc[i][j] = __builtin_amdgcn_mfma_f32_16x16x32_bf16(
                    af[i], bfr[j], acc[i][j], 0, 0, 0);
        tt++;
    };
    for (; tt < nt - 2; ) iter(IC<2 * LPT>{});
    iter(IC<LPT>{});
    iter(IC<0>{});
    #pragma unroll
    for (int i = 0; i < MR; i++) {
        #pragma unroll
        for (int j = 0; j < NR; j++) {
            int col = n0 + wn * (BN/2) + j * 16 + (lane & 15);
            #pragma unroll
            for (int r = 0; r < 4; r++) {
                int row = m0 + wm * (BM/2) + i * 16 + (lane >> 4) * 4 + r;
                float v = acc[i][j][r];
                if (resid) v += resid[(size_t)row * N + col];
                C[(size_t)row * N + col] = (OUT_T)v;
            }
        }
    }
}

// ------------------------- causal depthwise conv + SiLU, fused with dt softplus
__global__ __launch_bounds__(256) void convdt_kernel(
    const bf16* __restrict__ zx, const float* __restrict__ cw,
    const float* __restrict__ cb, const float* __restrict__ dt_bias,
    bf16* __restrict__ xs, bf16* __restrict__ Bm, bf16* __restrict__ Cm,
    float* __restrict__ dtb) {
    int idx = blockIdx.x * 256 + threadIdx.x;        // b*l*CDT
    int ch = idx % CDT;
    int bl = idx / CDT;
    if (ch >= CONVDIM) {                             // dt path
        int hh = ch - CONVDIM;
        float v = (float)zx[(size_t)bl * NPAD + DINNER + ch] + dt_bias[hh];
        dtb[bl * NHEADS + hh] = (v > 20.f) ? v : log1pf(expf(v));
        return;
    }
    int b = bl / SEQ, tt = bl % SEQ;
    float acc = cb[ch];
    #pragma unroll
    for (int k = 0; k < 4; k++) {
        int tp = tt - 3 + k;
        if (tp >= 0)
            acc += (float)zx[(size_t)(b * SEQ + tp) * NPAD + DINNER + ch] * cw[ch * 4 + k];
    }
    float s = acc / (1.f + expf(-acc));
    if (ch < DINNER)              xs[(size_t)bl * DINNER + ch] = (bf16)s;
    else if (ch < DINNER+DSTATE)  Bm[bl * DSTATE + (ch - DINNER)] = (bf16)s;
    else                          Cm[bl * DSTATE + (ch - DINNER - DSTATE)] = (bf16)s;
}

// ----------------------------------------- SSD: per-chunk local states (MFMA)
__global__ __launch_bounds__(256) void ssd_states_kernel(
    const bf16* __restrict__ xs, const bf16* __restrict__ Bm,
    const float* __restrict__ dtb, const float* __restrict__ A_log,
    bf16* __restrict__ states, float* __restrict__ Acs_g) {
    int blk = blockIdx.x;
    int hh = blk % NHEADS;
    int bc = blk / NHEADS;
    int c = bc % NCHUNK, b = bc / NCHUNK;
    __shared__ __align__(16) bf16 sXT[64 * SP];   // [p][l]
    __shared__ __align__(16) bf16 sBT[64 * SP];   // [n][l]
    __shared__ float dts[64], acs[64];
    int t = threadIdx.x;
    float Ah = -expf(A_log[hh]);
    if (t < 64) {                                // wave 0: load + parallel scan
        float dv = dtb[(b * SEQ + c * 64 + t) * NHEADS + hh];
        float v = dv * Ah;
        #pragma unroll
        for (int o = 1; o < 64; o <<= 1) {
            float p = __shfl_up(v, o);
            if (t >= o) v += p;
        }
        dts[t] = dv; acs[t] = v;
        Acs_g[((b * NHEADS + hh) * NCHUNK + c) * 64 + t] = v;
    }
    __syncthreads();
    float alast = acs[63];
    {   // stage transposed, weighted
        int l = t >> 2, c0 = (t & 3) * 16;
        int row = b * SEQ + c * 64 + l;
        float dl = dts[l];
        float wl = expf(alast - acs[l]);
        bf16x8 xv0 = *(const bf16x8*)&xs[(size_t)row * DINNER + hh * 64 + c0];
        bf16x8 xv1 = *(const bf16x8*)&xs[(size_t)row * DINNER + hh * 64 + c0 + 8];
        bf16x8 bv0 = *(const bf16x8*)&Bm[(size_t)row * DSTATE + c0];
        bf16x8 bv1 = *(const bf16x8*)&Bm[(size_t)row * DSTATE + c0 + 8];
        #pragma unroll
        for (int i = 0; i < 8; i++) {
            sXT[(c0 + i) * SP + l]     = (bf16)((float)xv0[i] * dl);
            sXT[(c0 + 8 + i) * SP + l] = (bf16)((float)xv1[i] * dl);
            sBT[(c0 + i) * SP + l]     = (bf16)((float)bv0[i] * wl);
            sBT[(c0 + 8 + i) * SP + l] = (bf16)((float)bv1[i] * wl);
        }
    }
    __syncthreads();
    int lane = t & 63, w = t >> 6;
    int wm = w >> 1, wn = w & 1;
    int fr = lane & 15, fc = (lane >> 4) * 8;
    f32x4 acc[2][2] = {};
    #pragma unroll
    for (int kk = 0; kk < 2; kk++) {
        bf16x8 a[2], bb[2];
        #pragma unroll
        for (int i = 0; i < 2; i++)
            a[i] = *(const bf16x8*)&sXT[(wm * 32 + i * 16 + fr) * SP + kk * 32 + fc];
        #pragma unroll
        for (int j = 0; j < 2; j++)
            bb[j] = *(const bf16x8*)&sBT[(wn * 32 + j * 16 + fr) * SP + kk * 32 + fc];
        #pragma unroll
        for (int i = 0; i < 2; i++)
            #pragma unroll
            for (int j = 0; j < 2; j++)
                acc[i][j] = __builtin_amdgcn_mfma_f32_16x16x32_bf16(
                    a[i], bb[j], acc[i][j], 0, 0, 0);
    }
    bf16* outp = states + (size_t)blk * 4096;
    #pragma unroll
    for (int i = 0; i < 2; i++)
        #pragma unroll
        for (int j = 0; j < 2; j++)
            #pragma unroll
            for (int r = 0; r < 4; r++)
                outp[(wm*32 + i*16 + (lane>>4)*4 + r) * 64 + wn*32 + j*16 + (lane&15)]
                    = (bf16)acc[i][j][r];
}

// ------------------------------------------- SSD: inter-chunk sequential scan
__global__ __launch_bounds__(256) void ssd_scan_kernel(
    bf16* __restrict__ states, const float* __restrict__ Acs_g) {
    int bid = blockIdx.x;
    int slice = bid & 3, bh = bid >> 2;
    int hh = bh % NHEADS, b = bh / NHEADS;
    int e0 = slice * 1024 + threadIdx.x * 4;
    bf16x4 loc[NCHUNK];
    float dec[NCHUNK];
    #pragma unroll
    for (int c = 0; c < NCHUNK; c++) {
        loc[c] = *(const bf16x4*)&states[(size_t)((b*NCHUNK+c)*NHEADS+hh)*4096 + e0];
        dec[c] = expf(Acs_g[((b*NHEADS+hh)*NCHUNK + c)*64 + 63]);
    }
    float S0 = 0.f, S1 = 0.f, S2 = 0.f, S3 = 0.f;
    #pragma unroll
    for (int c = 0; c < NCHUNK; c++) {
        bf16x4 l = loc[c];
        bf16x4 o; o[0] = (bf16)S0; o[1] = (bf16)S1; o[2] = (bf16)S2; o[3] = (bf16)S3;
        *(bf16x4*)&states[(size_t)((b*NCHUNK+c)*NHEADS+hh)*4096 + e0] = o;
        S0 = dec[c]*S0 + (float)l[0];
        S1 = dec[c]*S1 + (float)l[1];
        S2 = dec[c]*S2 + (float)l[2];
        S3 = dec[c]*S3 + (float)l[3];
    }
}

// --------------------------------- SSD: Y = Y_diag + Y_off + D*X (MFMA) -> bf16
__global__ __launch_bounds__(256) void ssd_out_kernel(
    const bf16* __restrict__ xs, const bf16* __restrict__ Bm,
    const bf16* __restrict__ Cm, const float* __restrict__ dtb,
    const bf16* __restrict__ states, const float* __restrict__ Acs_g,
    const float* __restrict__ Dv, bf16* __restrict__ Y) {
    int blk = blockIdx.x;
    int hh = blk % NHEADS;
    int bc = blk / NHEADS;
    int c = bc % NCHUNK, b = bc / NCHUNK;
    __shared__ __align__(16) bf16 sC [64 * SP];   // [l][n]
    __shared__ __align__(16) bf16 sBG[64 * SP];   // B[s][n] -> G'[l][s]
    __shared__ __align__(16) bf16 sXS[64 * SP];   // X^T[p][l] -> S[p][n]
    __shared__ float acs[64], dts[64];
    int t = threadIdx.x;
    bf16x8 sreg0, sreg1;                          // T14: S prefetch to regs
    {
        const bf16* sp = states + (size_t)blk * 4096 + t * 16;
        sreg0 = *(const bf16x8*)&sp[0];
        sreg1 = *(const bf16x8*)&sp[8];
    }
    if (t < 64) {
        acs[t] = Acs_g[((b * NHEADS + hh) * NCHUNK + c) * 64 + t];
        dts[t] = dtb[(b * SEQ + c * 64 + t) * NHEADS + hh];
    }
    {   // stage C, B natural; X transposed (raw)
        int l = t >> 2, c0 = (t & 3) * 16;
        int row = b * SEQ + c * 64 + l;
        *(bf16x8*)&sC[l * SP + c0]      = *(const bf16x8*)&Cm[(size_t)row * DSTATE + c0];
        *(bf16x8*)&sC[l * SP + c0 + 8]  = *(const bf16x8*)&Cm[(size_t)row * DSTATE + c0 + 8];
        *(bf16x8*)&sBG[l * SP + c0]     = *(const bf16x8*)&Bm[(size_t)row * DSTATE + c0];
        *(bf16x8*)&sBG[l * SP + c0 + 8] = *(const bf16x8*)&Bm[(size_t)row * DSTATE + c0 + 8];
        bf16x8 xv0 = *(const bf16x8*)&xs[(size_t)row * DINNER + hh * 64 + c0];
        bf16x8 xv1 = *(const bf16x8*)&xs[(size_t)row * DINNER + hh * 64 + c0 + 8];
        #pragma unroll
        for (int i = 0; i < 8; i++) {
            sXS[(c0 + i) * SP + l]     = xv0[i];
            sXS[(c0 + 8 + i) * SP + l] = xv1[i];
        }
    }
    __syncthreads();
    int lane = t & 63, w = t >> 6;
    int wm = w >> 1, wn = w & 1;
    int fr = lane & 15, fc = (lane >> 4) * 8;
    // ---- m1: G0 = C . B^T
    f32x4 g[2][2] = {};
    #pragma unroll
    for (int kk = 0; kk < 2; kk++) {
        bf16x8 a[2], bb[2];
        #pragma unroll
        for (int i = 0; i < 2; i++)
            a[i] = *(const bf16x8*)&sC[(wm * 32 + i * 16 + fr) * SP + kk * 32 + fc];
        #pragma unroll
        for (int j = 0; j < 2; j++)
            bb[j] = *(const bf16x8*)&sBG[(wn * 32 + j * 16 + fr) * SP + kk * 32 + fc];
        #pragma unroll
        for (int i = 0; i < 2; i++)
            #pragma unroll
            for (int j = 0; j < 2; j++)
                g[i][j] = __builtin_amdgcn_mfma_f32_16x16x32_bf16(a[i], bb[j], g[i][j], 0, 0, 0);
    }
    __syncthreads();           // all m1 reads of B done
    // ---- G' = tril(G0 * exp(acs_l - acs_s)) * dt_s
    #pragma unroll
    for (int i = 0; i < 2; i++) {
        #pragma unroll
        for (int j = 0; j < 2; j++) {
            int s = wn * 32 + j * 16 + (lane & 15);
            #pragma unroll
            for (int r = 0; r < 4; r++) {
                int l = wm * 32 + i * 16 + (lane >> 4) * 4 + r;
                float val = (s <= l) ? g[i][j][r] * expf(acs[l] - acs[s]) * dts[s] : 0.f;
                sBG[l * SP + s] = (bf16)val;
            }
        }
    }
    __syncthreads();           // G' visible
    // ---- m2: Y_diag = G' . X
    f32x4 yd[2][2] = {};
    #pragma unroll
    for (int kk = 0; kk < 2; kk++) {
        bf16x8 a[2], bb[2];
        #pragma unroll
        for (int i = 0; i < 2; i++)
            a[i] = *(const bf16x8*)&sBG[(wm * 32 + i * 16 + fr) * SP + kk * 32 + fc];
        #pragma unroll
        for (int j = 0; j < 2; j++)
            bb[j] = *(const bf16x8*)&sXS[(wn * 32 + j * 16 + fr) * SP + kk * 32 + fc];
        #pragma unroll
        for (int i = 0; i < 2; i++)
            #pragma unroll
            for (int j = 0; j < 2; j++)
                yd[i][j] = __builtin_amdgcn_mfma_f32_16x16x32_bf16(a[i], bb[j], yd[i][j], 0, 0, 0);
    }
    // raw X at output positions (D-skip), before sXS is overwritten
    float xk[2][2][4];
    #pragma unroll
    for (int i = 0; i < 2; i++)
        #pragma unroll
        for (int j = 0; j < 2; j++) {
            int p = wn * 32 + j * 16 + (lane & 15);
            #pragma unroll
            for (int r = 0; r < 4; r++) {
                int l = wm * 32 + i * 16 + (lane >> 4) * 4 + r;
                xk[i][j][r] = (float)sXS[p * SP + l];
            }
        }
    __syncthreads();           // all sXS (X^T) reads done
    {   // overwrite sXS with S_in [p][n]
        int p = t >> 2, n0 = (t & 3) * 16;
        *(bf16x8*)&sXS[p * SP + n0]     = sreg0;
        *(bf16x8*)&sXS[p * SP + n0 + 8] = sreg1;
    }
    __syncthreads();
    // ---- m3: Y_off = C . S^T
    f32x4 yo[2][2] = {};
    #pragma unroll
    for (int kk = 0; kk < 2; kk++) {
        bf16x8 a[2], bb[2];
        #pragma unroll
        for (int i = 0; i < 2; i++)
            a[i] = *(const bf16x8*)&sC[(wm * 32 + i * 16 + fr) * SP + kk * 32 + fc];
        #pragma unroll
        for (int j = 0; j < 2; j++)
            bb[j] = *(const bf16x8*)&sXS[(wn * 32 + j * 16 + fr) * SP + kk * 32 + fc];
        #pragma unroll
        for (int i = 0; i < 2; i++)
            #pragma unroll
            for (int j = 0; j < 2; j++)
                yo[i][j] = __builtin_amdgcn_mfma_f32_16x16x32_bf16(a[i], bb[j], yo[i][j], 0, 0, 0);
    }
    float Dh = Dv[hh];
    #pragma unroll
    for (int i = 0; i < 2; i++) {
        #pragma unroll
        for (int j = 0; j < 2; j++) {
            int p = wn * 32 + j * 16 + (lane & 15);
            #pragma unroll
            for (int r = 0; r < 4; r++) {
                int l = wm * 32 + i * 16 + (lane >> 4) * 4 + r;
                int row = b * SEQ + c * 64 + l;
                Y[(size_t)row * DINNER + hh * 64 + p] =
                    (bf16)(yd[i][j][r] + expf(acs[l]) * yo[i][j][r] + Dh * xk[i][j][r]);
            }
        }
    }
}

// --------------------------------------------------- gated RMSNorm -> bf16
__global__ __launch_bounds__(256) void rms_kernel(
    const bf16* __restrict__ Y, const bf16* __restrict__ zx,
    const float* __restrict__ nw, bf16* __restrict__ yn) {
    int row = blockIdx.x;
    const bf16* yr = Y + (size_t)row * DINNER;
    const bf16* zr = zx + (size_t)row * NPAD;       // z = cols [0, 2048)
    bf16* outr = yn + (size_t)row * DINNER;
    int t = threadIdx.x;
    float vals[8];
    float ss = 0.f;
    #pragma unroll
    for (int i = 0; i < 8; i++) {
        int idx = t + i * 256;
        float z = (float)zr[idx];
        float v = (float)yr[idx] * (z / (1.f + expf(-z)));
        vals[i] = v;
        ss += v * v;
    }
    for (int o = 32; o > 0; o >>= 1) ss += __shfl_down(ss, o);
    __shared__ float red[4];
    int wid = t >> 6, lane = t & 63;
    if (lane == 0) red[wid] = ss;
    __syncthreads();
    if (t == 0) { float a = 0; for (int i = 0; i < 4; i++) a += red[i]; red[0] = a; }
    __syncthreads();
    float r = rsqrtf(red[0] * (1.f / DINNER) + EPSF);
    #pragma unroll
    for (int i = 0; i < 8; i++) {
        int idx = t + i * 256;
        outr[idx] = (bf16)(vals[i] * r * nw[idx]);
    }
}

// ---------------------------------------------------------------------------
extern "C" void kernel_launch(void* const* d_in, const int* in_sizes, int n_in,
                              void* d_out, int out_size, void* d_ws, size_t ws_size,
                              hipStream_t stream) {
    const float* x          = (const float*)d_in[0];
    const float* ln_w       = (const float*)d_in[1];
    const float* ln_b       = (const float*)d_in[2];
    const float* in_proj_w  = (const float*)d_in[3];
    const float* conv_w     = (const float*)d_in[4];
    const float* conv_b     = (const float*)d_in[5];
    const float* dt_bias    = (const float*)d_in[6];
    const float* A_log      = (const float*)d_in[7];
    const float* Dv         = (const float*)d_in[8];
    const float* norm_w     = (const float*)d_in[9];
    const float* out_proj_w = (const float*)d_in[10];
    float* out = (float*)d_out;

    char* ws = (char*)d_ws;
    size_t off = 0;
    auto alloc = [&](size_t bytes) { char* p = ws + off; off += (bytes + 255) & ~(size_t)255; return p; };
    bf16*  h_bf  = (bf16*) alloc((size_t)4096 * DMODEL * 2);     //  8.4 MB
    bf16*  zx    = (bf16*) alloc((size_t)4096 * NPAD * 2);       // 35.6 MB
    bf16*  xs    = (bf16*) alloc((size_t)4096 * DINNER * 2);     // 16.8 MB
    bf16*  states= (bf16*) alloc((size_t)2048 * 4096 * 2);       // 16.8 MB
    bf16*  Yb    = (bf16*) alloc((size_t)4096 * DINNER * 2);     // 16.8 MB
    bf16*  Bt1   = (bf16*) alloc((size_t)NPAD * DMODEL * 2);     //  8.9 MB
    bf16*  Bt2   = (bf16*) alloc((size_t)DMODEL * DINNER * 2);   //  4.2 MB
    float* dtb   = (float*)alloc((size_t)4096 * NHEADS * 4);     //  0.5 MB
    float* Acs   = (float*)alloc((size_t)2 * NHEADS * NCHUNK * 64 * 4);
    bf16* Bm = h_bf;                          // h_bf dead after GEMM1
    bf16* Cm = h_bf + (size_t)4096 * DSTATE;
    bf16* yn = xs;                            // xs dead after ssd_out

    // weight transposes + LayerNorm, one launch
    pre_kernel<<<6400 + 4096, 256, 0, stream>>>(
        x, ln_w, ln_b, h_bf, in_proj_w, out_proj_w, Bt1, Bt2);

    {   // zx = h @ in_proj_w   (bf16 out)
        dim3 g(NPAD / 128, (BATCH * SEQ) / 128);
        gemm_bf16_pipe3<128, 128, bf16><<<g, 256, 0, stream>>>(
            h_bf, Bt1, zx, BATCH * SEQ, NPAD, DMODEL, nullptr);
    }

    convdt_kernel<<<(BATCH * SEQ * CDT) / 256, 256, 0, stream>>>(
        zx, conv_w, conv_b, dt_bias, xs, Bm, Cm, dtb);

    ssd_states_kernel<<<BATCH * NCHUNK * NHEADS, 256, 0, stream>>>(
        xs, Bm, dtb, A_log, states, Acs);

    ssd_scan_kernel<<<BATCH * NHEADS * 4, 256, 0, stream>>>(states, Acs);

    ssd_out_kernel<<<BATCH * NCHUNK * NHEADS, 256, 0, stream>>>(
        xs, Bm, Cm, dtb, states, Acs, Dv, Yb);

    rms_kernel<<<BATCH * SEQ, 256, 0, stream>>>(Yb, zx, norm_w, yn);

    {   // out = yn @ out_proj_w + x   (128x64 tiles -> 512 blocks)
        dim3 g(DMODEL / 64, (BATCH * SEQ) / 128);
        gemm_bf16_pipe3<128, 64, float><<<g, 256, 0, stream>>>(
            yn, Bt2, out, BATCH * SEQ, DMODEL, DINNER, x);
    }
}